// Round 1
// baseline (1607.423 us; speedup 1.0000x reference)
//
#include <hip/hip_runtime.h>
#include <hip/hip_bf16.h>

// GCN: 3x GraphConv(norm='both') + graph readout + dense head.
// Strategy:
//  - Build CSR by dst once per call (degree count -> scan -> atomic scatter).
//  - Algebra: (A*diag(ns)*h)*W == A*(diag(ns)*(h*W)); transform-first for
//    128->64 layers so ALL edge gathers are 64-feature (256B/edge).
//  - Layer epilogues fold the next layer's norm_src scaling into the stored h.
//  - Layer-3 epilogue atomicAdds directly into hg[64][64]; tiny dense kernel
//    finishes tanh(hg)@Wd+bd.

constexpr int NN = 100000;   // nodes
constexpr int NE = 3200000;  // edges
constexpr int NG = 64;       // graphs

// ---------------- degree / norm ----------------

__global__ __launch_bounds__(256) void degree_kernel(
    const int* __restrict__ src, const int* __restrict__ dst,
    int* __restrict__ dout, int* __restrict__ din, int e) {
  int i = blockIdx.x * 256 + threadIdx.x;
  if (i < e) {
    atomicAdd(&dout[src[i]], 1);
    atomicAdd(&din[dst[i]], 1);
  }
}

__global__ __launch_bounds__(256) void norm_kernel(
    const int* __restrict__ dout, const int* __restrict__ din,
    float* __restrict__ ns, float* __restrict__ nd, int n) {
  int i = blockIdx.x * 256 + threadIdx.x;
  if (i < n) {
    ns[i] = rsqrtf(fmaxf((float)dout[i], 1.0f));
    nd[i] = rsqrtf(fmaxf((float)din[i], 1.0f));
  }
}

// ---------------- exclusive scan (1024 elems / block) ----------------

__global__ __launch_bounds__(256) void scan1_kernel(
    const int* __restrict__ deg, int* __restrict__ row_off,
    int* __restrict__ bsums, int n) {
  __shared__ int s[256];
  int t = threadIdx.x;
  int base = blockIdx.x * 1024 + t * 4;
  int v0 = 0, v1 = 0, v2 = 0, v3 = 0;
  if (base + 0 < n) v0 = deg[base + 0];
  if (base + 1 < n) v1 = deg[base + 1];
  if (base + 2 < n) v2 = deg[base + 2];
  if (base + 3 < n) v3 = deg[base + 3];
  int sum = v0 + v1 + v2 + v3;
  s[t] = sum;
  __syncthreads();
  for (int off = 1; off < 256; off <<= 1) {
    int x = (t >= off) ? s[t - off] : 0;
    __syncthreads();
    s[t] += x;
    __syncthreads();
  }
  int excl = s[t] - sum;
  if (t == 255) bsums[blockIdx.x] = s[255];
  if (base + 0 < n) row_off[base + 0] = excl;
  if (base + 1 < n) row_off[base + 1] = excl + v0;
  if (base + 2 < n) row_off[base + 2] = excl + v0 + v1;
  if (base + 3 < n) row_off[base + 3] = excl + v0 + v1 + v2;
}

__global__ __launch_bounds__(128) void scan2_kernel(
    int* __restrict__ bsums, int nb, int* __restrict__ row_off, int n) {
  __shared__ int s[128];
  int t = threadIdx.x;
  int v = (t < nb) ? bsums[t] : 0;
  s[t] = v;
  __syncthreads();
  for (int off = 1; off < 128; off <<= 1) {
    int x = (t >= off) ? s[t - off] : 0;
    __syncthreads();
    s[t] += x;
    __syncthreads();
  }
  if (t < nb) bsums[t] = s[t] - v;  // exclusive prefix of block sums
  if (t == 127) row_off[n] = s[127];
}

__global__ __launch_bounds__(256) void scan3_kernel(
    int* __restrict__ row_off, const int* __restrict__ bsums, int n) {
  int i = blockIdx.x * 256 + threadIdx.x;
  if (i < n) row_off[i] += bsums[i >> 10];
}

// ---------------- CSR fill ----------------

__global__ __launch_bounds__(256) void fill_kernel(
    const int* __restrict__ src, const int* __restrict__ dst,
    const int* __restrict__ row_off, int* __restrict__ cursor,
    int* __restrict__ csr, int e) {
  int i = blockIdx.x * 256 + threadIdx.x;
  if (i < e) {
    int d = dst[i];
    int pos = row_off[d] + atomicAdd(&cursor[d], 1);
    csr[pos] = src[i];
  }
}

// ---------------- per-node GEMM (FIN -> 64), scaled by norm_src ----------------
// t[n][:] = (h[n][:] @ W) * ns[n]

template <int FIN>
__global__ __launch_bounds__(256) void gemm_ns_kernel(
    const float* __restrict__ h, const float* __restrict__ W,
    const float* __restrict__ ns, float* __restrict__ t, int n) {
  __shared__ float sW[FIN * 64];
  __shared__ float sM[4][FIN];
  for (int i = threadIdx.x; i < FIN * 64; i += 256) sW[i] = W[i];
  __syncthreads();
  int wid = threadIdx.x >> 6, lane = threadIdx.x & 63;
  int node = blockIdx.x * 4 + wid;
  if (node >= n) return;
#pragma unroll
  for (int i = 0; i < FIN / 64; ++i)
    sM[wid][lane + 64 * i] = h[node * FIN + lane + 64 * i];
  float o = 0.f;
#pragma unroll 8
  for (int k = 0; k < FIN; ++k) o += sM[wid][k] * sW[k * 64 + lane];
  t[node * 64 + lane] = o * ns[node];
}

// ---------------- 64-feature CSR gather core ----------------

__device__ __forceinline__ float gather64(const int* __restrict__ csr,
                                          const float* __restrict__ x,
                                          int rs, int re, int lane) {
  float acc = 0.f;
  for (int e0 = rs; e0 < re; e0 += 64) {
    int rem = re - e0;
    int sv = (lane < rem) ? csr[e0 + lane] : 0;
    int cnt = rem < 64 ? rem : 64;
    for (int j = 0; j < cnt; ++j) {
      int s = __shfl(sv, j);
      acc += x[s * 64 + lane];
    }
  }
  return acc;
}

// ---------------- layer 1 aggregate+epilogue ----------------
// h1s[n][j] = relu(seg(t1)*nd + b1[j]) * ns[n]

__global__ __launch_bounds__(256) void agg1_kernel(
    const int* __restrict__ row_off, const int* __restrict__ csr,
    const float* __restrict__ t, const float* __restrict__ nd,
    const float* __restrict__ ns, const float* __restrict__ b,
    float* __restrict__ out, int n) {
  int wid = threadIdx.x >> 6, lane = threadIdx.x & 63;
  int node = blockIdx.x * 4 + wid;
  if (node >= n) return;
  float acc = gather64(csr, t, row_off[node], row_off[node + 1], lane);
  float o = fmaxf(acc * nd[node] + b[lane], 0.f);
  out[node * 64 + lane] = o * ns[node];
}

// ---------------- layer 2 aggregate + fused 64->128 GEMM ----------------
// h2[n][:] = relu((seg(h1s)*nd) @ W2 + b2)

__global__ __launch_bounds__(256) void agg2_kernel(
    const int* __restrict__ row_off, const int* __restrict__ csr,
    const float* __restrict__ h1s, const float* __restrict__ nd,
    const float* __restrict__ W2, const float* __restrict__ b2,
    float* __restrict__ h2, int n) {
  __shared__ float sW[64 * 128];
  __shared__ float sB[128];
  __shared__ float sM[4][64];
  for (int i = threadIdx.x; i < 64 * 128; i += 256) sW[i] = W2[i];
  if (threadIdx.x < 128) sB[threadIdx.x] = b2[threadIdx.x];
  __syncthreads();
  int wid = threadIdx.x >> 6, lane = threadIdx.x & 63;
  int node = blockIdx.x * 4 + wid;
  if (node >= n) return;
  float acc = gather64(csr, h1s, row_off[node], row_off[node + 1], lane);
  acc *= nd[node];
  sM[wid][lane] = acc;  // same-wave write->read; compiler inserts waitcnt
  float o0 = sB[lane], o1 = sB[lane + 64];
#pragma unroll 8
  for (int k = 0; k < 64; ++k) {
    float mv = sM[wid][k];
    o0 += mv * sW[k * 128 + lane];
    o1 += mv * sW[k * 128 + lane + 64];
  }
  h2[node * 128 + lane] = fmaxf(o0, 0.f);
  h2[node * 128 + 64 + lane] = fmaxf(o1, 0.f);
}

// ---------------- layer 3 aggregate + readout atomics ----------------
// hg[g][j] += relu(seg(t3)*nd + b3[j])

__global__ __launch_bounds__(256) void agg3_kernel(
    const int* __restrict__ row_off, const int* __restrict__ csr,
    const float* __restrict__ t, const float* __restrict__ nd,
    const float* __restrict__ b, const int* __restrict__ gid,
    float* __restrict__ hg, int n) {
  int wid = threadIdx.x >> 6, lane = threadIdx.x & 63;
  int node = blockIdx.x * 4 + wid;
  if (node >= n) return;
  float acc = gather64(csr, t, row_off[node], row_off[node + 1], lane);
  float o = fmaxf(acc * nd[node] + b[lane], 0.f);
  atomicAdd(&hg[gid[node] * 64 + lane], o);
}

// ---------------- readout dense: out[g][c] = bd[c] + sum_k tanh(hg[g][k])*Wd[k][c]

__global__ __launch_bounds__(640) void readout_kernel(
    const float* __restrict__ hg, const float* __restrict__ Wd,
    const float* __restrict__ bd, float* __restrict__ out) {
  int t = threadIdx.x;  // 640 = 64 graphs * 10 classes
  int g = t / 10, c = t % 10;
  float o = bd[c];
#pragma unroll 8
  for (int k = 0; k < 64; ++k) o += tanhf(hg[g * 64 + k]) * Wd[k * 10 + c];
  out[t] = o;
}

// ---------------- launch ----------------

extern "C" void kernel_launch(void* const* d_in, const int* in_sizes, int n_in,
                              void* d_out, int out_size, void* d_ws, size_t ws_size,
                              hipStream_t stream) {
  const float* in_feat = (const float*)d_in[0];
  const int* src = (const int*)d_in[1];
  const int* dst = (const int*)d_in[2];
  const int* gid = (const int*)d_in[3];
  const float* W1 = (const float*)d_in[4];
  const float* b1 = (const float*)d_in[5];
  const float* W2 = (const float*)d_in[6];
  const float* b2 = (const float*)d_in[7];
  const float* W3 = (const float*)d_in[8];
  const float* b3 = (const float*)d_in[9];
  const float* Wd = (const float*)d_in[10];
  const float* bd = (const float*)d_in[11];
  float* out = (float*)d_out;

  // workspace layout (~118 MB)
  char* ws = (char*)d_ws;
  size_t o = 0;
  auto alloc = [&](size_t bytes) -> char* {
    char* p = ws + o;
    o = (o + bytes + 1023) & ~(size_t)1023;
    return p;
  };
  int* deg_out = (int*)alloc(NN * 4);
  int* deg_in = (int*)alloc(NN * 4);
  int* cursor = (int*)alloc(NN * 4);
  float* hg = (float*)alloc(NG * 64 * 4);
  size_t zero_bytes = o;  // everything above must start at 0
  float* norm_src = (float*)alloc(NN * 4);
  float* norm_dst = (float*)alloc(NN * 4);
  int* row_off = (int*)alloc((NN + 1) * 4);
  int* bsums = (int*)alloc(512);
  int* csr = (int*)alloc((size_t)NE * 4);
  float* tbuf = (float*)alloc((size_t)NN * 64 * 4);  // t1, then reused for t3
  float* h1s = (float*)alloc((size_t)NN * 64 * 4);
  float* h2 = (float*)alloc((size_t)NN * 128 * 4);
  (void)ws_size;

  hipMemsetAsync(d_ws, 0, zero_bytes, stream);

  const int egrid = (NE + 255) / 256;        // 12500
  const int ngrid = (NN + 255) / 256;        // 391
  const int sgrid = (NN + 1023) / 1024;      // 98
  const int wgrid = (NN + 3) / 4;            // 25000 (wave-per-node)

  degree_kernel<<<egrid, 256, 0, stream>>>(src, dst, deg_out, deg_in, NE);
  norm_kernel<<<ngrid, 256, 0, stream>>>(deg_out, deg_in, norm_src, norm_dst, NN);
  scan1_kernel<<<sgrid, 256, 0, stream>>>(deg_in, row_off, bsums, NN);
  scan2_kernel<<<1, 128, 0, stream>>>(bsums, sgrid, row_off, NN);
  scan3_kernel<<<ngrid, 256, 0, stream>>>(row_off, bsums, NN);
  fill_kernel<<<egrid, 256, 0, stream>>>(src, dst, row_off, cursor, csr, NE);

  // layer 1: transform-first (128->64), then aggregate
  gemm_ns_kernel<128><<<wgrid, 256, 0, stream>>>(in_feat, W1, norm_src, tbuf, NN);
  agg1_kernel<<<wgrid, 256, 0, stream>>>(row_off, csr, tbuf, norm_dst, norm_src,
                                         b1, h1s, NN);
  // layer 2: aggregate-first (64->128), fused GEMM epilogue
  agg2_kernel<<<wgrid, 256, 0, stream>>>(row_off, csr, h1s, norm_dst, W2, b2,
                                         h2, NN);
  // layer 3: transform-first (128->64), aggregate + readout atomics
  gemm_ns_kernel<128><<<wgrid, 256, 0, stream>>>(h2, W3, norm_src, tbuf, NN);
  agg3_kernel<<<wgrid, 256, 0, stream>>>(row_off, csr, tbuf, norm_dst, b3, gid,
                                         hg, NN);
  readout_kernel<<<1, 640, 0, stream>>>(hg, Wd, bd, out);
}

// Round 2
// 1226.862 us; speedup vs baseline: 1.3102x; 1.3102x over previous
//
#include <hip/hip_runtime.h>
#include <hip/hip_bf16.h>

// GCN: 3x GraphConv(norm='both') + graph readout + dense head.
// Strategy:
//  - Build CSR by dst once per call (degree count -> scan -> atomic scatter).
//  - Algebra: (A*diag(ns)*h)*W == A*(diag(ns)*(h*W)); transform-first for
//    128->64 layers so ALL edge gathers are 64-feature (256B/edge).
//  - gather64 batches edges in unrolled groups of 16: 16 bpermutes, then 16
//    independent global loads in flight, then predicated accumulate. (R1:
//    serial per-edge chain was latency-bound — VALUBusy 24%, HBM 13%.)
//  - Layer-3 epilogue atomicAdds into hg[64][64]; tiny dense head finishes.

constexpr int NN = 100000;   // nodes
constexpr int NE = 3200000;  // edges
constexpr int NG = 64;       // graphs

// ---------------- degree / norm ----------------

__global__ __launch_bounds__(256) void degree_kernel(
    const int* __restrict__ src, const int* __restrict__ dst,
    int* __restrict__ dout, int* __restrict__ din, int e) {
  int i = blockIdx.x * 256 + threadIdx.x;
  if (i < e) {
    atomicAdd(&dout[src[i]], 1);
    atomicAdd(&din[dst[i]], 1);
  }
}

__global__ __launch_bounds__(256) void norm_kernel(
    const int* __restrict__ dout, const int* __restrict__ din,
    float* __restrict__ ns, float* __restrict__ nd, int n) {
  int i = blockIdx.x * 256 + threadIdx.x;
  if (i < n) {
    ns[i] = rsqrtf(fmaxf((float)dout[i], 1.0f));
    nd[i] = rsqrtf(fmaxf((float)din[i], 1.0f));
  }
}

// ---------------- exclusive scan (1024 elems / block) ----------------

__global__ __launch_bounds__(256) void scan1_kernel(
    const int* __restrict__ deg, int* __restrict__ row_off,
    int* __restrict__ bsums, int n) {
  __shared__ int s[256];
  int t = threadIdx.x;
  int base = blockIdx.x * 1024 + t * 4;
  int v0 = 0, v1 = 0, v2 = 0, v3 = 0;
  if (base + 0 < n) v0 = deg[base + 0];
  if (base + 1 < n) v1 = deg[base + 1];
  if (base + 2 < n) v2 = deg[base + 2];
  if (base + 3 < n) v3 = deg[base + 3];
  int sum = v0 + v1 + v2 + v3;
  s[t] = sum;
  __syncthreads();
  for (int off = 1; off < 256; off <<= 1) {
    int x = (t >= off) ? s[t - off] : 0;
    __syncthreads();
    s[t] += x;
    __syncthreads();
  }
  int excl = s[t] - sum;
  if (t == 255) bsums[blockIdx.x] = s[255];
  if (base + 0 < n) row_off[base + 0] = excl;
  if (base + 1 < n) row_off[base + 1] = excl + v0;
  if (base + 2 < n) row_off[base + 2] = excl + v0 + v1;
  if (base + 3 < n) row_off[base + 3] = excl + v0 + v1 + v2;
}

__global__ __launch_bounds__(128) void scan2_kernel(
    int* __restrict__ bsums, int nb, int* __restrict__ row_off, int n) {
  __shared__ int s[128];
  int t = threadIdx.x;
  int v = (t < nb) ? bsums[t] : 0;
  s[t] = v;
  __syncthreads();
  for (int off = 1; off < 128; off <<= 1) {
    int x = (t >= off) ? s[t - off] : 0;
    __syncthreads();
    s[t] += x;
    __syncthreads();
  }
  if (t < nb) bsums[t] = s[t] - v;  // exclusive prefix of block sums
  if (t == 127) row_off[n] = s[127];
}

__global__ __launch_bounds__(256) void scan3_kernel(
    int* __restrict__ row_off, const int* __restrict__ bsums, int n) {
  int i = blockIdx.x * 256 + threadIdx.x;
  if (i < n) row_off[i] += bsums[i >> 10];
}

// ---------------- CSR fill ----------------

__global__ __launch_bounds__(256) void fill_kernel(
    const int* __restrict__ src, const int* __restrict__ dst,
    const int* __restrict__ row_off, int* __restrict__ cursor,
    int* __restrict__ csr, int e) {
  int i = blockIdx.x * 256 + threadIdx.x;
  if (i < e) {
    int d = dst[i];
    int pos = row_off[d] + atomicAdd(&cursor[d], 1);
    csr[pos] = src[i];
  }
}

// ---------------- per-node GEMM (FIN -> 64), scaled by norm_src ----------------
// t[n][:] = (h[n][:] @ W) * ns[n]

template <int FIN>
__global__ __launch_bounds__(256) void gemm_ns_kernel(
    const float* __restrict__ h, const float* __restrict__ W,
    const float* __restrict__ ns, float* __restrict__ t, int n) {
  __shared__ float sW[FIN * 64];
  __shared__ float sM[4][FIN];
  for (int i = threadIdx.x; i < FIN * 64; i += 256) sW[i] = W[i];
  __syncthreads();
  int wid = threadIdx.x >> 6, lane = threadIdx.x & 63;
  int node = blockIdx.x * 4 + wid;
  if (node >= n) return;
#pragma unroll
  for (int i = 0; i < FIN / 64; ++i)
    sM[wid][lane + 64 * i] = h[node * FIN + lane + 64 * i];
  float o = 0.f;
#pragma unroll 8
  for (int k = 0; k < FIN; ++k) o += sM[wid][k] * sW[k * 64 + lane];
  t[node * 64 + lane] = o * ns[node];
}

// ---------------- 64-feature CSR gather core ----------------
// Batched: 16 shfls -> 16 independent loads in flight -> predicated adds.
// Invalid lanes carry index 0 (x[0..63] is a hot line — harmless traffic).

__device__ __forceinline__ float gather64(const int* __restrict__ csr,
                                          const float* __restrict__ x,
                                          int rs, int re, int lane) {
  float acc = 0.f;
  for (int e0 = rs; e0 < re; e0 += 64) {
    int idx = e0 + lane;
    int sv = (idx < re) ? csr[idx] : 0;
    int cnt = re - e0;
    if (cnt > 64) cnt = 64;
#pragma unroll
    for (int jb = 0; jb < 64; jb += 16) {
      if (jb < cnt) {  // wave-uniform
        int ss[16];
        float vv[16];
#pragma unroll
        for (int u = 0; u < 16; ++u) ss[u] = __shfl(sv, jb + u);
#pragma unroll
        for (int u = 0; u < 16; ++u) vv[u] = x[(size_t)ss[u] * 64 + lane];
#pragma unroll
        for (int u = 0; u < 16; ++u) acc += (jb + u < cnt) ? vv[u] : 0.f;
      }
    }
  }
  return acc;
}

// ---------------- layer 1 aggregate+epilogue ----------------
// h1s[n][j] = relu(seg(t1)*nd + b1[j]) * ns[n]

__global__ __launch_bounds__(256) void agg1_kernel(
    const int* __restrict__ row_off, const int* __restrict__ csr,
    const float* __restrict__ t, const float* __restrict__ nd,
    const float* __restrict__ ns, const float* __restrict__ b,
    float* __restrict__ out, int n) {
  int wid = threadIdx.x >> 6, lane = threadIdx.x & 63;
  int node = blockIdx.x * 4 + wid;
  if (node >= n) return;
  float acc = gather64(csr, t, row_off[node], row_off[node + 1], lane);
  float o = fmaxf(acc * nd[node] + b[lane], 0.f);
  out[node * 64 + lane] = o * ns[node];
}

// ---------------- layer 2 aggregate + fused 64->128 GEMM ----------------
// h2[n][:] = relu((seg(h1s)*nd) @ W2 + b2)

__global__ __launch_bounds__(256) void agg2_kernel(
    const int* __restrict__ row_off, const int* __restrict__ csr,
    const float* __restrict__ h1s, const float* __restrict__ nd,
    const float* __restrict__ W2, const float* __restrict__ b2,
    float* __restrict__ h2, int n) {
  __shared__ float sW[64 * 128];
  __shared__ float sB[128];
  __shared__ float sM[4][64];
  for (int i = threadIdx.x; i < 64 * 128; i += 256) sW[i] = W2[i];
  if (threadIdx.x < 128) sB[threadIdx.x] = b2[threadIdx.x];
  __syncthreads();
  int wid = threadIdx.x >> 6, lane = threadIdx.x & 63;
  int node = blockIdx.x * 4 + wid;
  if (node >= n) return;
  float acc = gather64(csr, h1s, row_off[node], row_off[node + 1], lane);
  acc *= nd[node];
  sM[wid][lane] = acc;  // same-wave write->read; compiler inserts waitcnt
  float o0 = sB[lane], o1 = sB[lane + 64];
#pragma unroll 8
  for (int k = 0; k < 64; ++k) {
    float mv = sM[wid][k];
    o0 += mv * sW[k * 128 + lane];
    o1 += mv * sW[k * 128 + lane + 64];
  }
  h2[node * 128 + lane] = fmaxf(o0, 0.f);
  h2[node * 128 + 64 + lane] = fmaxf(o1, 0.f);
}

// ---------------- layer 3 aggregate + readout atomics ----------------
// hg[g][j] += relu(seg(t3)*nd + b3[j])

__global__ __launch_bounds__(256) void agg3_kernel(
    const int* __restrict__ row_off, const int* __restrict__ csr,
    const float* __restrict__ t, const float* __restrict__ nd,
    const float* __restrict__ b, const int* __restrict__ gid,
    float* __restrict__ hg, int n) {
  int wid = threadIdx.x >> 6, lane = threadIdx.x & 63;
  int node = blockIdx.x * 4 + wid;
  if (node >= n) return;
  float acc = gather64(csr, t, row_off[node], row_off[node + 1], lane);
  float o = fmaxf(acc * nd[node] + b[lane], 0.f);
  atomicAdd(&hg[gid[node] * 64 + lane], o);
}

// ---------------- readout dense: out[g][c] = bd[c] + sum_k tanh(hg[g][k])*Wd[k][c]

__global__ __launch_bounds__(640) void readout_kernel(
    const float* __restrict__ hg, const float* __restrict__ Wd,
    const float* __restrict__ bd, float* __restrict__ out) {
  int t = threadIdx.x;  // 640 = 64 graphs * 10 classes
  int g = t / 10, c = t % 10;
  float o = bd[c];
#pragma unroll 8
  for (int k = 0; k < 64; ++k) o += tanhf(hg[g * 64 + k]) * Wd[k * 10 + c];
  out[t] = o;
}

// ---------------- launch ----------------

extern "C" void kernel_launch(void* const* d_in, const int* in_sizes, int n_in,
                              void* d_out, int out_size, void* d_ws, size_t ws_size,
                              hipStream_t stream) {
  const float* in_feat = (const float*)d_in[0];
  const int* src = (const int*)d_in[1];
  const int* dst = (const int*)d_in[2];
  const int* gid = (const int*)d_in[3];
  const float* W1 = (const float*)d_in[4];
  const float* b1 = (const float*)d_in[5];
  const float* W2 = (const float*)d_in[6];
  const float* b2 = (const float*)d_in[7];
  const float* W3 = (const float*)d_in[8];
  const float* b3 = (const float*)d_in[9];
  const float* Wd = (const float*)d_in[10];
  const float* bd = (const float*)d_in[11];
  float* out = (float*)d_out;

  // workspace layout (~118 MB)
  char* ws = (char*)d_ws;
  size_t o = 0;
  auto alloc = [&](size_t bytes) -> char* {
    char* p = ws + o;
    o = (o + bytes + 1023) & ~(size_t)1023;
    return p;
  };
  int* deg_out = (int*)alloc(NN * 4);
  int* deg_in = (int*)alloc(NN * 4);
  int* cursor = (int*)alloc(NN * 4);
  float* hg = (float*)alloc(NG * 64 * 4);
  size_t zero_bytes = o;  // everything above must start at 0
  float* norm_src = (float*)alloc(NN * 4);
  float* norm_dst = (float*)alloc(NN * 4);
  int* row_off = (int*)alloc((NN + 1) * 4);
  int* bsums = (int*)alloc(512);
  int* csr = (int*)alloc((size_t)NE * 4);
  float* tbuf = (float*)alloc((size_t)NN * 64 * 4);  // t1, then reused for t3
  float* h1s = (float*)alloc((size_t)NN * 64 * 4);
  float* h2 = (float*)alloc((size_t)NN * 128 * 4);
  (void)ws_size;

  hipMemsetAsync(d_ws, 0, zero_bytes, stream);

  const int egrid = (NE + 255) / 256;        // 12500
  const int ngrid = (NN + 255) / 256;        // 391
  const int sgrid = (NN + 1023) / 1024;      // 98
  const int wgrid = (NN + 3) / 4;            // 25000 (wave-per-node)

  degree_kernel<<<egrid, 256, 0, stream>>>(src, dst, deg_out, deg_in, NE);
  norm_kernel<<<ngrid, 256, 0, stream>>>(deg_out, deg_in, norm_src, norm_dst, NN);
  scan1_kernel<<<sgrid, 256, 0, stream>>>(deg_in, row_off, bsums, NN);
  scan2_kernel<<<1, 128, 0, stream>>>(bsums, sgrid, row_off, NN);
  scan3_kernel<<<ngrid, 256, 0, stream>>>(row_off, bsums, NN);
  fill_kernel<<<egrid, 256, 0, stream>>>(src, dst, row_off, cursor, csr, NE);

  // layer 1: transform-first (128->64), then aggregate
  gemm_ns_kernel<128><<<wgrid, 256, 0, stream>>>(in_feat, W1, norm_src, tbuf, NN);
  agg1_kernel<<<wgrid, 256, 0, stream>>>(row_off, csr, tbuf, norm_dst, norm_src,
                                         b1, h1s, NN);
  // layer 2: aggregate-first (64->128), fused GEMM epilogue
  agg2_kernel<<<wgrid, 256, 0, stream>>>(row_off, csr, h1s, norm_dst, W2, b2,
                                         h2, NN);
  // layer 3: transform-first (128->64), aggregate + readout atomics
  gemm_ns_kernel<128><<<wgrid, 256, 0, stream>>>(h2, W3, norm_src, tbuf, NN);
  agg3_kernel<<<wgrid, 256, 0, stream>>>(row_off, csr, tbuf, norm_dst, b3, gid,
                                         hg, NN);
  readout_kernel<<<1, 640, 0, stream>>>(hg, Wd, bd, out);
}

// Round 3
// 872.381 us; speedup vs baseline: 1.8426x; 1.4063x over previous
//
#include <hip/hip_runtime.h>
#include <hip/hip_bf16.h>

// GCN: 3x GraphConv(norm='both') + graph readout + dense head.
// Strategy:
//  - ATOMIC-FREE CSR build (R2: 6.4M device atomics in degree_kernel wrote
//    199MB through the coherence point, 244us at 26G atomics/s):
//      hist (LDS 8-bit packed histograms per 32K-edge chunk, local rank from
//      LDS-atomic return) -> reduce (packed byte-lane sum + chunk-exclusive
//      prefix P) -> scan -> fill (pos = row_off + P + lrank, no atomics).
//  - Algebra: (A*diag(ns)*h)*W == A*(diag(ns)*(h*W)); transform-first for
//    128->64 layers so ALL edge gathers are 64-feature (256B/edge).
//  - gather64 batches edges in groups of 16: 16 shfls, 16 loads in flight,
//    predicated accumulate (R1: serial chain was latency-bound).
//  - Layer-3 epilogue atomicAdds into hg[64][64]; tiny dense head finishes.

constexpr int NN = 100000;   // nodes
constexpr int NE = 3200000;  // edges
constexpr int NG = 64;       // graphs

constexpr int CBITS = 15;
constexpr int CHUNK = 1 << CBITS;                 // 32768 edges/chunk
constexpr int NCHUNK = (NE + CHUNK - 1) / CHUNK;  // 98
constexpr int WORDS = NN / 4;                     // 25000 packed u8x4 words
constexpr int HWORDS = WORDS / 2;                 // 12500 (half node range)

// ---------------- chunked LDS histogram ----------------
// grid (NCHUNK, 2 arrays, 2 node-ranges). 8-bit packed bins: per-chunk
// per-node counts are ~Poisson(0.33), far below 255 -> no byte carries.
// y==0: dst (also records local rank from the LDS-atomic return value).

__global__ __launch_bounds__(1024) void hist_kernel(
    const int* __restrict__ src, const int* __restrict__ dst,
    uint* __restrict__ pdst, uint* __restrict__ psrc,
    unsigned char* __restrict__ lrank) {
  __shared__ uint bins[HWORDS];  // 50KB
  for (int i = threadIdx.x; i < HWORDS; i += 1024) bins[i] = 0;
  __syncthreads();
  const int c = blockIdx.x, r = blockIdx.z;
  const int nlo = r * (NN / 2), nhi = nlo + NN / 2;
  const int wbase = r * HWORDS;
  const int start = c << CBITS;
  const int end = min(start + CHUNK, NE);
  const int* idx = (blockIdx.y == 0) ? dst : src;
  if (blockIdx.y == 0) {
    for (int i = start + threadIdx.x; i < end; i += 1024) {
      int n = idx[i];
      if (n >= nlo && n < nhi) {
        uint old = atomicAdd(&bins[(n >> 2) - wbase], 1u << ((n & 3) * 8));
        lrank[i] = (unsigned char)(old >> ((n & 3) * 8));
      }
    }
  } else {
    for (int i = start + threadIdx.x; i < end; i += 1024) {
      int n = idx[i];
      if (n >= nlo && n < nhi)
        atomicAdd(&bins[(n >> 2) - wbase], 1u << ((n & 3) * 8));
    }
  }
  __syncthreads();
  uint* pp = ((blockIdx.y == 0) ? pdst : psrc) + (size_t)c * WORDS + wbase;
  for (int i = threadIdx.x; i < HWORDS; i += 1024) pp[i] = bins[i];
}

// ---------------- reduce: deg + chunk-exclusive prefix ----------------
// Byte-lane adds can't carry: per-node total degree < 255.

__global__ __launch_bounds__(256) void reduce_kernel(
    const uint* __restrict__ partial, uint* __restrict__ P,
    int* __restrict__ deg) {
  int w = blockIdx.x * 256 + threadIdx.x;
  if (w >= WORDS) return;
  uint run = 0;
  if (P != nullptr) {
#pragma unroll 7
    for (int c = 0; c < NCHUNK; ++c) {
      uint v = partial[(size_t)c * WORDS + w];
      P[(size_t)c * WORDS + w] = run;
      run += v;
    }
  } else {
#pragma unroll 7
    for (int c = 0; c < NCHUNK; ++c) run += partial[(size_t)c * WORDS + w];
  }
  ((int4*)deg)[w] = make_int4(run & 0xff, (run >> 8) & 0xff,
                              (run >> 16) & 0xff, (run >> 24) & 0xff);
}

__global__ __launch_bounds__(256) void norm_kernel(
    const int* __restrict__ dout, const int* __restrict__ din,
    float* __restrict__ ns, float* __restrict__ nd, int n) {
  int i = blockIdx.x * 256 + threadIdx.x;
  if (i < n) {
    ns[i] = rsqrtf(fmaxf((float)dout[i], 1.0f));
    nd[i] = rsqrtf(fmaxf((float)din[i], 1.0f));
  }
}

// ---------------- exclusive scan (1024 elems / block) ----------------

__global__ __launch_bounds__(256) void scan1_kernel(
    const int* __restrict__ deg, int* __restrict__ row_off,
    int* __restrict__ bsums, int n) {
  __shared__ int s[256];
  int t = threadIdx.x;
  int base = blockIdx.x * 1024 + t * 4;
  int v0 = 0, v1 = 0, v2 = 0, v3 = 0;
  if (base + 0 < n) v0 = deg[base + 0];
  if (base + 1 < n) v1 = deg[base + 1];
  if (base + 2 < n) v2 = deg[base + 2];
  if (base + 3 < n) v3 = deg[base + 3];
  int sum = v0 + v1 + v2 + v3;
  s[t] = sum;
  __syncthreads();
  for (int off = 1; off < 256; off <<= 1) {
    int x = (t >= off) ? s[t - off] : 0;
    __syncthreads();
    s[t] += x;
    __syncthreads();
  }
  int excl = s[t] - sum;
  if (t == 255) bsums[blockIdx.x] = s[255];
  if (base + 0 < n) row_off[base + 0] = excl;
  if (base + 1 < n) row_off[base + 1] = excl + v0;
  if (base + 2 < n) row_off[base + 2] = excl + v0 + v1;
  if (base + 3 < n) row_off[base + 3] = excl + v0 + v1 + v2;
}

__global__ __launch_bounds__(128) void scan2_kernel(
    int* __restrict__ bsums, int nb, int* __restrict__ row_off, int n) {
  __shared__ int s[128];
  int t = threadIdx.x;
  int v = (t < nb) ? bsums[t] : 0;
  s[t] = v;
  __syncthreads();
  for (int off = 1; off < 128; off <<= 1) {
    int x = (t >= off) ? s[t - off] : 0;
    __syncthreads();
    s[t] += x;
    __syncthreads();
  }
  if (t < nb) bsums[t] = s[t] - v;
  if (t == 127) row_off[n] = s[127];
}

__global__ __launch_bounds__(256) void scan3_kernel(
    int* __restrict__ row_off, const int* __restrict__ bsums, int n) {
  int i = blockIdx.x * 256 + threadIdx.x;
  if (i < n) row_off[i] += bsums[i >> 10];
}

// ---------------- CSR fill (atomic-free) ----------------

__global__ __launch_bounds__(256) void fill_kernel(
    const int* __restrict__ src, const int* __restrict__ dst,
    const int* __restrict__ row_off, const unsigned char* __restrict__ Pb,
    const unsigned char* __restrict__ lrank, int* __restrict__ csr, int e) {
  int i = blockIdx.x * 256 + threadIdx.x;
  if (i < e) {
    int d = dst[i];
    int c = i >> CBITS;
    int pos = row_off[d] + (int)Pb[(size_t)c * NN + d] + (int)lrank[i];
    csr[pos] = src[i];
  }
}

// ---------------- per-node GEMM (FIN -> 64), scaled by norm_src ----------------
// t[n][:] = (h[n][:] @ W) * ns[n]

template <int FIN>
__global__ __launch_bounds__(256) void gemm_ns_kernel(
    const float* __restrict__ h, const float* __restrict__ W,
    const float* __restrict__ ns, float* __restrict__ t, int n) {
  __shared__ float sW[FIN * 64];
  __shared__ float sM[4][FIN];
  for (int i = threadIdx.x; i < FIN * 64; i += 256) sW[i] = W[i];
  __syncthreads();
  int wid = threadIdx.x >> 6, lane = threadIdx.x & 63;
  int node = blockIdx.x * 4 + wid;
  if (node >= n) return;
#pragma unroll
  for (int i = 0; i < FIN / 64; ++i)
    sM[wid][lane + 64 * i] = h[node * FIN + lane + 64 * i];
  float o = 0.f;
#pragma unroll 8
  for (int k = 0; k < FIN; ++k) o += sM[wid][k] * sW[k * 64 + lane];
  t[node * 64 + lane] = o * ns[node];
}

// ---------------- 64-feature CSR gather core ----------------
// Batched: 16 shfls -> 16 independent loads in flight -> predicated adds.

__device__ __forceinline__ float gather64(const int* __restrict__ csr,
                                          const float* __restrict__ x,
                                          int rs, int re, int lane) {
  float acc = 0.f;
  for (int e0 = rs; e0 < re; e0 += 64) {
    int idx = e0 + lane;
    int sv = (idx < re) ? csr[idx] : 0;
    int cnt = re - e0;
    if (cnt > 64) cnt = 64;
#pragma unroll
    for (int jb = 0; jb < 64; jb += 16) {
      if (jb < cnt) {  // wave-uniform
        int ss[16];
        float vv[16];
#pragma unroll
        for (int u = 0; u < 16; ++u) ss[u] = __shfl(sv, jb + u);
#pragma unroll
        for (int u = 0; u < 16; ++u) vv[u] = x[(size_t)ss[u] * 64 + lane];
#pragma unroll
        for (int u = 0; u < 16; ++u) acc += (jb + u < cnt) ? vv[u] : 0.f;
      }
    }
  }
  return acc;
}

// ---------------- layer 1 aggregate+epilogue ----------------

__global__ __launch_bounds__(256) void agg1_kernel(
    const int* __restrict__ row_off, const int* __restrict__ csr,
    const float* __restrict__ t, const float* __restrict__ nd,
    const float* __restrict__ ns, const float* __restrict__ b,
    float* __restrict__ out, int n) {
  int wid = threadIdx.x >> 6, lane = threadIdx.x & 63;
  int node = blockIdx.x * 4 + wid;
  if (node >= n) return;
  float acc = gather64(csr, t, row_off[node], row_off[node + 1], lane);
  float o = fmaxf(acc * nd[node] + b[lane], 0.f);
  out[node * 64 + lane] = o * ns[node];
}

// ---------------- layer 2 aggregate + fused 64->128 GEMM ----------------

__global__ __launch_bounds__(256) void agg2_kernel(
    const int* __restrict__ row_off, const int* __restrict__ csr,
    const float* __restrict__ h1s, const float* __restrict__ nd,
    const float* __restrict__ W2, const float* __restrict__ b2,
    float* __restrict__ h2, int n) {
  __shared__ float sW[64 * 128];
  __shared__ float sB[128];
  __shared__ float sM[4][64];
  for (int i = threadIdx.x; i < 64 * 128; i += 256) sW[i] = W2[i];
  if (threadIdx.x < 128) sB[threadIdx.x] = b2[threadIdx.x];
  __syncthreads();
  int wid = threadIdx.x >> 6, lane = threadIdx.x & 63;
  int node = blockIdx.x * 4 + wid;
  if (node >= n) return;
  float acc = gather64(csr, h1s, row_off[node], row_off[node + 1], lane);
  acc *= nd[node];
  sM[wid][lane] = acc;
  float o0 = sB[lane], o1 = sB[lane + 64];
#pragma unroll 8
  for (int k = 0; k < 64; ++k) {
    float mv = sM[wid][k];
    o0 += mv * sW[k * 128 + lane];
    o1 += mv * sW[k * 128 + lane + 64];
  }
  h2[node * 128 + lane] = fmaxf(o0, 0.f);
  h2[node * 128 + 64 + lane] = fmaxf(o1, 0.f);
}

// ---------------- layer 3 aggregate + readout atomics ----------------

__global__ __launch_bounds__(256) void agg3_kernel(
    const int* __restrict__ row_off, const int* __restrict__ csr,
    const float* __restrict__ t, const float* __restrict__ nd,
    const float* __restrict__ b, const int* __restrict__ gid,
    float* __restrict__ hg, int n) {
  int wid = threadIdx.x >> 6, lane = threadIdx.x & 63;
  int node = blockIdx.x * 4 + wid;
  if (node >= n) return;
  float acc = gather64(csr, t, row_off[node], row_off[node + 1], lane);
  float o = fmaxf(acc * nd[node] + b[lane], 0.f);
  atomicAdd(&hg[gid[node] * 64 + lane], o);
}

// ---------------- readout dense ----------------

__global__ __launch_bounds__(640) void readout_kernel(
    const float* __restrict__ hg, const float* __restrict__ Wd,
    const float* __restrict__ bd, float* __restrict__ out) {
  int t = threadIdx.x;  // 640 = 64 graphs * 10 classes
  int g = t / 10, c = t % 10;
  float o = bd[c];
#pragma unroll 8
  for (int k = 0; k < 64; ++k) o += tanhf(hg[g * 64 + k]) * Wd[k * 10 + c];
  out[t] = o;
}

// ---------------- launch ----------------

extern "C" void kernel_launch(void* const* d_in, const int* in_sizes, int n_in,
                              void* d_out, int out_size, void* d_ws, size_t ws_size,
                              hipStream_t stream) {
  const float* in_feat = (const float*)d_in[0];
  const int* src = (const int*)d_in[1];
  const int* dst = (const int*)d_in[2];
  const int* gid = (const int*)d_in[3];
  const float* W1 = (const float*)d_in[4];
  const float* b1 = (const float*)d_in[5];
  const float* W2 = (const float*)d_in[6];
  const float* b2 = (const float*)d_in[7];
  const float* W3 = (const float*)d_in[8];
  const float* b3 = (const float*)d_in[9];
  const float* Wd = (const float*)d_in[10];
  const float* bd = (const float*)d_in[11];
  float* out = (float*)d_out;

  // workspace layout (~117 MB peak, with overlays)
  char* ws = (char*)d_ws;
  size_t o = 0;
  auto alloc = [&](size_t bytes) -> char* {
    char* p = ws + o;
    o = (o + bytes + 1023) & ~(size_t)1023;
    return p;
  };
  float* hg = (float*)alloc(NG * 64 * 4);
  size_t zero_bytes = o;  // only hg needs zero-init
  int* deg_out = (int*)alloc(NN * 4);
  int* deg_in = (int*)alloc(NN * 4);
  float* norm_src = (float*)alloc(NN * 4);
  float* norm_dst = (float*)alloc(NN * 4);
  int* row_off = (int*)alloc((NN + 1) * 4);
  int* bsums = (int*)alloc(512);
  int* csr = (int*)alloc((size_t)NE * 4);
  float* tbuf = (float*)alloc((size_t)NN * 64 * 4);  // t1, then t3
  float* h1s = (float*)alloc((size_t)NN * 64 * 4);
  float* h2 = (float*)alloc((size_t)NN * 128 * 4);
  (void)ws_size;

  // overlays (dead before their hosts are written):
  uint* psrc = (uint*)tbuf;                              // dead before gemm1
  uint* Pw = (uint*)h2;                                  // 9.8MB
  unsigned char* lrank = (unsigned char*)h2 + 9800704;   // 3.2MB
  uint* pdst = (uint*)((char*)h2 + 13001728);            // 9.8MB; all dead before agg2

  hipMemsetAsync(d_ws, 0, zero_bytes, stream);

  const int egrid = (NE + 255) / 256;    // 12500
  const int ngrid = (NN + 255) / 256;    // 391
  const int sgrid = (NN + 1023) / 1024;  // 98
  const int wgrid = (NN + 3) / 4;        // 25000 (wave-per-node)
  const int rgrid = (WORDS + 255) / 256; // 98

  hist_kernel<<<dim3(NCHUNK, 2, 2), 1024, 0, stream>>>(src, dst, pdst, psrc, lrank);
  reduce_kernel<<<rgrid, 256, 0, stream>>>(pdst, Pw, deg_in);
  reduce_kernel<<<rgrid, 256, 0, stream>>>(psrc, nullptr, deg_out);
  norm_kernel<<<ngrid, 256, 0, stream>>>(deg_out, deg_in, norm_src, norm_dst, NN);
  scan1_kernel<<<sgrid, 256, 0, stream>>>(deg_in, row_off, bsums, NN);
  scan2_kernel<<<1, 128, 0, stream>>>(bsums, sgrid, row_off, NN);
  scan3_kernel<<<ngrid, 256, 0, stream>>>(row_off, bsums, NN);
  fill_kernel<<<egrid, 256, 0, stream>>>(src, dst, row_off,
                                         (const unsigned char*)Pw, lrank, csr, NE);

  // layer 1: transform-first (128->64), then aggregate
  gemm_ns_kernel<128><<<wgrid, 256, 0, stream>>>(in_feat, W1, norm_src, tbuf, NN);
  agg1_kernel<<<wgrid, 256, 0, stream>>>(row_off, csr, tbuf, norm_dst, norm_src,
                                         b1, h1s, NN);
  // layer 2: aggregate-first (64->128), fused GEMM epilogue
  agg2_kernel<<<wgrid, 256, 0, stream>>>(row_off, csr, h1s, norm_dst, W2, b2,
                                         h2, NN);
  // layer 3: transform-first (128->64), aggregate + readout atomics
  gemm_ns_kernel<128><<<wgrid, 256, 0, stream>>>(h2, W3, norm_src, tbuf, NN);
  agg3_kernel<<<wgrid, 256, 0, stream>>>(row_off, csr, tbuf, norm_dst, b3, gid,
                                         hg, NN);
  readout_kernel<<<1, 640, 0, stream>>>(hg, Wd, bd, out);
}

// Round 4
// 720.195 us; speedup vs baseline: 2.2319x; 1.2113x over previous
//
#include <hip/hip_runtime.h>
#include <hip/hip_bf16.h>

// GCN: 3x GraphConv(norm='both') + graph readout + dense head.
// Strategy:
//  - ATOMIC-FREE CSR build (R2: 6.4M device atomics = 26G/s ceiling):
//      hist (LDS 8-bit packed chunk histograms, local rank from LDS-atomic
//      return) -> reduce (byte-lane sums + chunk-exclusive prefix) -> scan ->
//      fill (pos = row_off + P + lrank, no atomics).
//  - Algebra: (A*diag(ns)*h)*W == A*(diag(ns)*(h*W)); transform-first for
//    128->64 layers so ALL edge gathers are 64-feature rows.
//  - R3: gathers were scattered-address-rate + byte bound. Features stored
//    bf16 (128B rows); gather loads uint4 (8 bf16) per lane, 8 lanes/edge ->
//    8 edges per wave-load (8x fewer scattered addresses, 2x fewer bytes).
//    fp32 accumulate + shfl_xor butterfly over the 8 edge-groups.
//  - R3: agg3's 6.4M hg atomics were at the atomic ceiling. Now 1024-thread
//    blocks reduce 16 nodes in LDS -> 1 atomic row per block (0.4M atomics).

constexpr int NN = 100000;   // nodes
constexpr int NE = 3200000;  // edges
constexpr int NG = 64;       // graphs

constexpr int CBITS = 15;
constexpr int CHUNK = 1 << CBITS;                 // 32768 edges/chunk
constexpr int NCHUNK = (NE + CHUNK - 1) / CHUNK;  // 98
constexpr int WORDS = NN / 4;                     // 25000 packed u8x4 words
constexpr int HWORDS = WORDS / 2;                 // 12500 (half node range)

// ---------------- chunked LDS histogram ----------------

__global__ __launch_bounds__(1024) void hist_kernel(
    const int* __restrict__ src, const int* __restrict__ dst,
    uint* __restrict__ pdst, uint* __restrict__ psrc,
    unsigned char* __restrict__ lrank) {
  __shared__ uint bins[HWORDS];  // 50KB
  for (int i = threadIdx.x; i < HWORDS; i += 1024) bins[i] = 0;
  __syncthreads();
  const int c = blockIdx.x, r = blockIdx.z;
  const int nlo = r * (NN / 2), nhi = nlo + NN / 2;
  const int wbase = r * HWORDS;
  const int start = c << CBITS;
  const int end = min(start + CHUNK, NE);
  const int* idx = (blockIdx.y == 0) ? dst : src;
  if (blockIdx.y == 0) {
    for (int i = start + threadIdx.x; i < end; i += 1024) {
      int n = idx[i];
      if (n >= nlo && n < nhi) {
        uint old = atomicAdd(&bins[(n >> 2) - wbase], 1u << ((n & 3) * 8));
        lrank[i] = (unsigned char)(old >> ((n & 3) * 8));
      }
    }
  } else {
    for (int i = start + threadIdx.x; i < end; i += 1024) {
      int n = idx[i];
      if (n >= nlo && n < nhi)
        atomicAdd(&bins[(n >> 2) - wbase], 1u << ((n & 3) * 8));
    }
  }
  __syncthreads();
  uint* pp = ((blockIdx.y == 0) ? pdst : psrc) + (size_t)c * WORDS + wbase;
  for (int i = threadIdx.x; i < HWORDS; i += 1024) pp[i] = bins[i];
}

// ---------------- reduce: deg + chunk-exclusive prefix ----------------

__global__ __launch_bounds__(256) void reduce_kernel(
    const uint* __restrict__ partial, uint* __restrict__ P,
    int* __restrict__ deg) {
  int w = blockIdx.x * 256 + threadIdx.x;
  if (w >= WORDS) return;
  uint run = 0;
  if (P != nullptr) {
#pragma unroll 7
    for (int c = 0; c < NCHUNK; ++c) {
      uint v = partial[(size_t)c * WORDS + w];
      P[(size_t)c * WORDS + w] = run;
      run += v;
    }
  } else {
#pragma unroll 7
    for (int c = 0; c < NCHUNK; ++c) run += partial[(size_t)c * WORDS + w];
  }
  ((int4*)deg)[w] = make_int4(run & 0xff, (run >> 8) & 0xff,
                              (run >> 16) & 0xff, (run >> 24) & 0xff);
}

__global__ __launch_bounds__(256) void norm_kernel(
    const int* __restrict__ dout, const int* __restrict__ din,
    float* __restrict__ ns, float* __restrict__ nd, int n) {
  int i = blockIdx.x * 256 + threadIdx.x;
  if (i < n) {
    ns[i] = rsqrtf(fmaxf((float)dout[i], 1.0f));
    nd[i] = rsqrtf(fmaxf((float)din[i], 1.0f));
  }
}

// ---------------- exclusive scan (1024 elems / block) ----------------

__global__ __launch_bounds__(256) void scan1_kernel(
    const int* __restrict__ deg, int* __restrict__ row_off,
    int* __restrict__ bsums, int n) {
  __shared__ int s[256];
  int t = threadIdx.x;
  int base = blockIdx.x * 1024 + t * 4;
  int v0 = 0, v1 = 0, v2 = 0, v3 = 0;
  if (base + 0 < n) v0 = deg[base + 0];
  if (base + 1 < n) v1 = deg[base + 1];
  if (base + 2 < n) v2 = deg[base + 2];
  if (base + 3 < n) v3 = deg[base + 3];
  int sum = v0 + v1 + v2 + v3;
  s[t] = sum;
  __syncthreads();
  for (int off = 1; off < 256; off <<= 1) {
    int x = (t >= off) ? s[t - off] : 0;
    __syncthreads();
    s[t] += x;
    __syncthreads();
  }
  int excl = s[t] - sum;
  if (t == 255) bsums[blockIdx.x] = s[255];
  if (base + 0 < n) row_off[base + 0] = excl;
  if (base + 1 < n) row_off[base + 1] = excl + v0;
  if (base + 2 < n) row_off[base + 2] = excl + v0 + v1;
  if (base + 3 < n) row_off[base + 3] = excl + v0 + v1 + v2;
}

__global__ __launch_bounds__(128) void scan2_kernel(
    int* __restrict__ bsums, int nb, int* __restrict__ row_off, int n) {
  __shared__ int s[128];
  int t = threadIdx.x;
  int v = (t < nb) ? bsums[t] : 0;
  s[t] = v;
  __syncthreads();
  for (int off = 1; off < 128; off <<= 1) {
    int x = (t >= off) ? s[t - off] : 0;
    __syncthreads();
    s[t] += x;
    __syncthreads();
  }
  if (t < nb) bsums[t] = s[t] - v;
  if (t == 127) row_off[n] = s[127];
}

__global__ __launch_bounds__(256) void scan3_kernel(
    int* __restrict__ row_off, const int* __restrict__ bsums, int n) {
  int i = blockIdx.x * 256 + threadIdx.x;
  if (i < n) row_off[i] += bsums[i >> 10];
}

// ---------------- CSR fill (atomic-free) ----------------

__global__ __launch_bounds__(256) void fill_kernel(
    const int* __restrict__ src, const int* __restrict__ dst,
    const int* __restrict__ row_off, const unsigned char* __restrict__ Pb,
    const unsigned char* __restrict__ lrank, int* __restrict__ csr, int e) {
  int i = blockIdx.x * 256 + threadIdx.x;
  if (i < e) {
    int d = dst[i];
    int c = i >> CBITS;
    int pos = row_off[d] + (int)Pb[(size_t)c * NN + d] + (int)lrank[i];
    csr[pos] = src[i];
  }
}

// ---------------- bf16 helpers ----------------

__device__ __forceinline__ uint pack_bf16(float a, float b) {
  uint ua = __float_as_uint(a), ub = __float_as_uint(b);
  ua = (ua + 0x7fffu + ((ua >> 16) & 1u)) >> 16;          // RNE
  ub = (ub + 0x7fffu + ((ub >> 16) & 1u)) & 0xffff0000u;  // RNE
  return ua | ub;  // a -> low (even feature), b -> high (odd feature)
}

__device__ __forceinline__ ushort to_bf16(float a) {
  uint ua = __float_as_uint(a);
  return (ushort)((ua + 0x7fffu + ((ua >> 16) & 1u)) >> 16);
}

__device__ __forceinline__ void acc8_add(float* acc, uint4 v) {
  acc[0] += __uint_as_float(v.x << 16);
  acc[1] += __uint_as_float(v.x & 0xffff0000u);
  acc[2] += __uint_as_float(v.y << 16);
  acc[3] += __uint_as_float(v.y & 0xffff0000u);
  acc[4] += __uint_as_float(v.z << 16);
  acc[5] += __uint_as_float(v.z & 0xffff0000u);
  acc[6] += __uint_as_float(v.w << 16);
  acc[7] += __uint_as_float(v.w & 0xffff0000u);
}

// ---------------- 64-feature bf16 CSR gather ----------------
// 8 lanes per edge (lane = 8*eg + fl); lane loads uint4 = 8 bf16 features
// [8*fl .. 8*fl+7]. One wave-load covers 8 edges. fp32 accumulate, then
// shfl_xor butterfly over the 8 edge-groups -> every lane has acc[8] totals.

__device__ __forceinline__ void gather64_bf16(const int* __restrict__ csr,
                                              const ushort* __restrict__ x,
                                              int rs, int re, int lane,
                                              float* acc) {
  const int eg = lane >> 3;
  const int fl = lane & 7;
  for (int e0 = rs; e0 < re; e0 += 64) {
    int idx = e0 + lane;
    int sv = (idx < re) ? csr[idx] : 0;
    int cnt = re - e0;
    if (cnt > 64) cnt = 64;
#pragma unroll
    for (int j = 0; j < 8; ++j) {
      int jb = j * 8;
      if (jb + 8 <= cnt) {  // full sub-batch (wave-uniform)
        int s = __shfl(sv, jb + eg);
        uint4 v = *(const uint4*)(x + (size_t)s * 64 + fl * 8);
        acc8_add(acc, v);
      } else if (jb < cnt) {  // partial sub-batch
        int s = __shfl(sv, jb + eg);
        uint m = (jb + eg < cnt) ? 0xffffffffu : 0u;
        uint4 v = *(const uint4*)(x + (size_t)s * 64 + fl * 8);
        v.x &= m; v.y &= m; v.z &= m; v.w &= m;
        acc8_add(acc, v);
      }
    }
  }
#pragma unroll
  for (int k = 0; k < 8; ++k) {
    acc[k] += __shfl_xor(acc[k], 8);
    acc[k] += __shfl_xor(acc[k], 16);
    acc[k] += __shfl_xor(acc[k], 32);
  }
}

// ---------------- per-node GEMM (FIN -> 64), scaled, bf16 out ----------------
// t[n][:] = bf16((h[n][:] @ W) * ns[n])

template <int FIN>
__global__ __launch_bounds__(256) void gemm_ns_kernel(
    const float* __restrict__ h, const float* __restrict__ W,
    const float* __restrict__ ns, ushort* __restrict__ t, int n) {
  __shared__ float sW[FIN * 64];
  __shared__ float sM[4][FIN];
  for (int i = threadIdx.x; i < FIN * 64; i += 256) sW[i] = W[i];
  __syncthreads();
  int wid = threadIdx.x >> 6, lane = threadIdx.x & 63;
  int node = blockIdx.x * 4 + wid;
  if (node >= n) return;
#pragma unroll
  for (int i = 0; i < FIN / 64; ++i)
    sM[wid][lane + 64 * i] = h[(size_t)node * FIN + lane + 64 * i];
  float o = 0.f;
#pragma unroll 8
  for (int k = 0; k < FIN; ++k) o += sM[wid][k] * sW[k * 64 + lane];
  t[(size_t)node * 64 + lane] = to_bf16(o * ns[node]);
}

// ---------------- layer 1 aggregate + epilogue (bf16 out) ----------------
// h1s[n][j] = bf16(relu(seg(t1)*nd + b1[j]) * ns[n])

__global__ __launch_bounds__(256) void agg1_kernel(
    const int* __restrict__ row_off, const int* __restrict__ csr,
    const ushort* __restrict__ t, const float* __restrict__ nd,
    const float* __restrict__ ns, const float* __restrict__ b,
    ushort* __restrict__ out, int n) {
  int wid = threadIdx.x >> 6, lane = threadIdx.x & 63;
  int node = blockIdx.x * 4 + wid;
  if (node >= n) return;
  float acc[8] = {0, 0, 0, 0, 0, 0, 0, 0};
  gather64_bf16(csr, t, row_off[node], row_off[node + 1], lane, acc);
  int fl = lane & 7;
  float ndv = nd[node], nsv = ns[node];
  const float4* bp = (const float4*)(b + fl * 8);
  float4 b0 = bp[0], b1v = bp[1];
  float o[8];
  o[0] = fmaxf(acc[0] * ndv + b0.x, 0.f) * nsv;
  o[1] = fmaxf(acc[1] * ndv + b0.y, 0.f) * nsv;
  o[2] = fmaxf(acc[2] * ndv + b0.z, 0.f) * nsv;
  o[3] = fmaxf(acc[3] * ndv + b0.w, 0.f) * nsv;
  o[4] = fmaxf(acc[4] * ndv + b1v.x, 0.f) * nsv;
  o[5] = fmaxf(acc[5] * ndv + b1v.y, 0.f) * nsv;
  o[6] = fmaxf(acc[6] * ndv + b1v.z, 0.f) * nsv;
  o[7] = fmaxf(acc[7] * ndv + b1v.w, 0.f) * nsv;
  if ((lane >> 3) == 0) {
    uint4 v;
    v.x = pack_bf16(o[0], o[1]);
    v.y = pack_bf16(o[2], o[3]);
    v.z = pack_bf16(o[4], o[5]);
    v.w = pack_bf16(o[6], o[7]);
    *(uint4*)(out + (size_t)node * 64 + fl * 8) = v;
  }
}

// ---------------- layer 2 aggregate + fused 64->128 GEMM (fp32 out) ----------

__global__ __launch_bounds__(256) void agg2_kernel(
    const int* __restrict__ row_off, const int* __restrict__ csr,
    const ushort* __restrict__ h1s, const float* __restrict__ nd,
    const float* __restrict__ W2, const float* __restrict__ b2,
    float* __restrict__ h2, int n) {
  __shared__ float sW[64 * 128];
  __shared__ float sB[128];
  __shared__ float sM[4][64];
  for (int i = threadIdx.x; i < 64 * 128; i += 256) sW[i] = W2[i];
  if (threadIdx.x < 128) sB[threadIdx.x] = b2[threadIdx.x];
  __syncthreads();
  int wid = threadIdx.x >> 6, lane = threadIdx.x & 63;
  int node = blockIdx.x * 4 + wid;
  if (node >= n) return;
  float acc[8] = {0, 0, 0, 0, 0, 0, 0, 0};
  gather64_bf16(csr, h1s, row_off[node], row_off[node + 1], lane, acc);
  float ndv = nd[node];
  int fl = lane & 7;
  if ((lane >> 3) == 0) {
#pragma unroll
    for (int k = 0; k < 8; ++k) sM[wid][fl * 8 + k] = acc[k] * ndv;
  }
  float o0 = sB[lane], o1 = sB[lane + 64];
#pragma unroll 8
  for (int k = 0; k < 64; ++k) {
    float mv = sM[wid][k];
    o0 += mv * sW[k * 128 + lane];
    o1 += mv * sW[k * 128 + lane + 64];
  }
  h2[(size_t)node * 128 + lane] = fmaxf(o0, 0.f);
  h2[(size_t)node * 128 + 64 + lane] = fmaxf(o1, 0.f);
}

// ---------------- layer 3 aggregate + block-reduced readout ----------------
// 1024 threads = 16 nodes/block; LDS tree-reduce -> 1 atomic row per block
// when the block's 16 nodes share a graph id (gids sorted: ~99% of blocks).

__global__ __launch_bounds__(1024) void agg3_kernel(
    const int* __restrict__ row_off, const int* __restrict__ csr,
    const ushort* __restrict__ t, const float* __restrict__ nd,
    const float* __restrict__ b, const int* __restrict__ gid,
    float* __restrict__ hg, int n) {
  __shared__ float sO[16][64];
  __shared__ int sG[16];
  __shared__ int uni;
  int wid = threadIdx.x >> 6, lane = threadIdx.x & 63;
  int node = blockIdx.x * 16 + wid;  // NN % 16 == 0: always valid
  float acc[8] = {0, 0, 0, 0, 0, 0, 0, 0};
  gather64_bf16(csr, t, row_off[node], row_off[node + 1], lane, acc);
  int fl = lane & 7;
  float ndv = nd[node];
  const float4* bp = (const float4*)(b + fl * 8);
  float4 b0 = bp[0], b1v = bp[1];
  if ((lane >> 3) == 0) {
    sO[wid][fl * 8 + 0] = fmaxf(acc[0] * ndv + b0.x, 0.f);
    sO[wid][fl * 8 + 1] = fmaxf(acc[1] * ndv + b0.y, 0.f);
    sO[wid][fl * 8 + 2] = fmaxf(acc[2] * ndv + b0.z, 0.f);
    sO[wid][fl * 8 + 3] = fmaxf(acc[3] * ndv + b0.w, 0.f);
    sO[wid][fl * 8 + 4] = fmaxf(acc[4] * ndv + b1v.x, 0.f);
    sO[wid][fl * 8 + 5] = fmaxf(acc[5] * ndv + b1v.y, 0.f);
    sO[wid][fl * 8 + 6] = fmaxf(acc[6] * ndv + b1v.z, 0.f);
    sO[wid][fl * 8 + 7] = fmaxf(acc[7] * ndv + b1v.w, 0.f);
  }
  if (lane == 0) sG[wid] = gid[node];
  __syncthreads();
  if (threadIdx.x == 0) {
    int g0 = sG[0], u = 1;
#pragma unroll
    for (int i = 1; i < 16; ++i) u &= (sG[i] == g0);
    uni = u;
  }
  __syncthreads();
  if (uni) {
#pragma unroll
    for (int s = 8; s >= 1; s >>= 1) {
      if (wid < s) sO[wid][lane] += sO[wid + s][lane];
      __syncthreads();
    }
    if (threadIdx.x < 64) atomicAdd(&hg[sG[0] * 64 + lane], sO[0][lane]);
  } else {
    atomicAdd(&hg[sG[wid] * 64 + lane], sO[wid][lane]);
  }
}

// ---------------- readout dense ----------------

__global__ __launch_bounds__(640) void readout_kernel(
    const float* __restrict__ hg, const float* __restrict__ Wd,
    const float* __restrict__ bd, float* __restrict__ out) {
  int t = threadIdx.x;  // 640 = 64 graphs * 10 classes
  int g = t / 10, c = t % 10;
  float o = bd[c];
#pragma unroll 8
  for (int k = 0; k < 64; ++k) o += tanhf(hg[g * 64 + k]) * Wd[k * 10 + c];
  out[t] = o;
}

// ---------------- launch ----------------

extern "C" void kernel_launch(void* const* d_in, const int* in_sizes, int n_in,
                              void* d_out, int out_size, void* d_ws, size_t ws_size,
                              hipStream_t stream) {
  const float* in_feat = (const float*)d_in[0];
  const int* src = (const int*)d_in[1];
  const int* dst = (const int*)d_in[2];
  const int* gid = (const int*)d_in[3];
  const float* W1 = (const float*)d_in[4];
  const float* b1 = (const float*)d_in[5];
  const float* W2 = (const float*)d_in[6];
  const float* b2 = (const float*)d_in[7];
  const float* W3 = (const float*)d_in[8];
  const float* b3 = (const float*)d_in[9];
  const float* Wd = (const float*)d_in[10];
  const float* bd = (const float*)d_in[11];
  float* out = (float*)d_out;

  char* ws = (char*)d_ws;
  size_t o = 0;
  auto alloc = [&](size_t bytes) -> char* {
    char* p = ws + o;
    o = (o + bytes + 1023) & ~(size_t)1023;
    return p;
  };
  float* hg = (float*)alloc(NG * 64 * 4);
  size_t zero_bytes = o;  // only hg needs zero-init
  int* deg_out = (int*)alloc(NN * 4);
  int* deg_in = (int*)alloc(NN * 4);
  float* norm_src = (float*)alloc(NN * 4);
  float* norm_dst = (float*)alloc(NN * 4);
  int* row_off = (int*)alloc((NN + 1) * 4);
  int* bsums = (int*)alloc(512);
  int* csr = (int*)alloc((size_t)NE * 4);
  ushort* tbuf = (ushort*)alloc((size_t)NN * 64 * 4);  // bf16 t1/t3 (half used; hosts psrc overlay)
  ushort* h1s = (ushort*)alloc((size_t)NN * 64 * 2);   // bf16
  float* h2 = (float*)alloc((size_t)NN * 128 * 4);
  (void)ws_size;

  // overlays (dead before their hosts are written):
  uint* psrc = (uint*)tbuf;                             // 9.8MB, dead before gemm1
  uint* Pw = (uint*)h2;                                 // 9.8MB
  unsigned char* lrank = (unsigned char*)h2 + 9800704;  // 3.2MB
  uint* pdst = (uint*)((char*)h2 + 13001728);           // 9.8MB; dead before agg2

  hipMemsetAsync(d_ws, 0, zero_bytes, stream);

  const int egrid = (NE + 255) / 256;     // 12500
  const int ngrid = (NN + 255) / 256;     // 391
  const int sgrid = (NN + 1023) / 1024;   // 98
  const int wgrid = (NN + 3) / 4;         // 25000 (wave-per-node)
  const int rgrid = (WORDS + 255) / 256;  // 98

  hist_kernel<<<dim3(NCHUNK, 2, 2), 1024, 0, stream>>>(src, dst, pdst, psrc, lrank);
  reduce_kernel<<<rgrid, 256, 0, stream>>>(pdst, Pw, deg_in);
  reduce_kernel<<<rgrid, 256, 0, stream>>>(psrc, nullptr, deg_out);
  norm_kernel<<<ngrid, 256, 0, stream>>>(deg_out, deg_in, norm_src, norm_dst, NN);
  scan1_kernel<<<sgrid, 256, 0, stream>>>(deg_in, row_off, bsums, NN);
  scan2_kernel<<<1, 128, 0, stream>>>(bsums, sgrid, row_off, NN);
  scan3_kernel<<<ngrid, 256, 0, stream>>>(row_off, bsums, NN);
  fill_kernel<<<egrid, 256, 0, stream>>>(src, dst, row_off,
                                         (const unsigned char*)Pw, lrank, csr, NE);

  // layer 1: transform-first (128->64), then aggregate
  gemm_ns_kernel<128><<<wgrid, 256, 0, stream>>>(in_feat, W1, norm_src, tbuf, NN);
  agg1_kernel<<<wgrid, 256, 0, stream>>>(row_off, csr, tbuf, norm_dst, norm_src,
                                         b1, h1s, NN);
  // layer 2: aggregate-first (64->128), fused GEMM epilogue
  agg2_kernel<<<wgrid, 256, 0, stream>>>(row_off, csr, h1s, norm_dst, W2, b2,
                                         h2, NN);
  // layer 3: transform-first (128->64), aggregate + block-reduced readout
  gemm_ns_kernel<128><<<wgrid, 256, 0, stream>>>(h2, W3, norm_src, tbuf, NN);
  agg3_kernel<<<NN / 16, 1024, 0, stream>>>(row_off, csr, tbuf, norm_dst, b3,
                                            gid, hg, NN);
  readout_kernel<<<1, 640, 0, stream>>>(hg, Wd, bd, out);
}

// Round 5
// 496.566 us; speedup vs baseline: 3.2371x; 1.4504x over previous
//
#include <hip/hip_runtime.h>
#include <hip/hip_bf16.h>

// GCN: 3x GraphConv(norm='both') + graph readout + dense head.
// Strategy:
//  - ATOMIC-FREE CSR build (R2: device atomics cap at ~26G/s):
//      hist (LDS 8-bit packed chunk histograms, local rank from LDS-atomic
//      return) -> reduce (byte-lane sums + chunk-exclusive prefix) -> scan ->
//      fill (pos = row_off + P + lrank, no atomics).
//  - Algebra: (A*diag(ns)*h)*W == A*(diag(ns)*(h*W)); transform-first for
//    128->64 layers so ALL edge gathers are 64-feature rows.
//  - bf16 features; gather loads uint4 (8 bf16)/lane, 8 lanes/edge -> 8 edges
//    per wave-load; fp32 accumulate + shfl_xor butterfly (R3).
//  - R4: agg2's scalar LDS epilogue was LDS-pipe-saturated (128 ds_read_b32
//    per node ~ 87% of runtime); gemm_ns likewise. ALL dense multiplies now
//    MFMA (16x16x32 bf16): agg2 is gather-only; 3 skinny gemm_mfma kernels
//    (W pre-transposed to bf16 Wt[n][k]) do the transforms.
//  - agg3: 1024-thread blocks reduce 16 nodes in LDS -> ~1 atomic row/block.

constexpr int NN = 100000;   // nodes
constexpr int NE = 3200000;  // edges
constexpr int NG = 64;       // graphs

constexpr int CBITS = 15;
constexpr int CHUNK = 1 << CBITS;                 // 32768 edges/chunk
constexpr int NCHUNK = (NE + CHUNK - 1) / CHUNK;  // 98
constexpr int WORDS = NN / 4;                     // 25000 packed u8x4 words
constexpr int HWORDS = WORDS / 2;                 // 12500 (half node range)

typedef __attribute__((ext_vector_type(8))) short short8;
typedef __attribute__((ext_vector_type(4))) float f32x4;

// ---------------- chunked LDS histogram ----------------

__global__ __launch_bounds__(1024) void hist_kernel(
    const int* __restrict__ src, const int* __restrict__ dst,
    uint* __restrict__ pdst, uint* __restrict__ psrc,
    unsigned char* __restrict__ lrank) {
  __shared__ uint bins[HWORDS];  // 50KB
  for (int i = threadIdx.x; i < HWORDS; i += 1024) bins[i] = 0;
  __syncthreads();
  const int c = blockIdx.x, r = blockIdx.z;
  const int nlo = r * (NN / 2), nhi = nlo + NN / 2;
  const int wbase = r * HWORDS;
  const int start = c << CBITS;
  const int end = min(start + CHUNK, NE);
  const int* idx = (blockIdx.y == 0) ? dst : src;
  if (blockIdx.y == 0) {
    for (int i = start + threadIdx.x; i < end; i += 1024) {
      int n = idx[i];
      if (n >= nlo && n < nhi) {
        uint old = atomicAdd(&bins[(n >> 2) - wbase], 1u << ((n & 3) * 8));
        lrank[i] = (unsigned char)(old >> ((n & 3) * 8));
      }
    }
  } else {
    for (int i = start + threadIdx.x; i < end; i += 1024) {
      int n = idx[i];
      if (n >= nlo && n < nhi)
        atomicAdd(&bins[(n >> 2) - wbase], 1u << ((n & 3) * 8));
    }
  }
  __syncthreads();
  uint* pp = ((blockIdx.y == 0) ? pdst : psrc) + (size_t)c * WORDS + wbase;
  for (int i = threadIdx.x; i < HWORDS; i += 1024) pp[i] = bins[i];
}

// ---------------- reduce: deg + chunk-exclusive prefix ----------------

__global__ __launch_bounds__(256) void reduce_kernel(
    const uint* __restrict__ partial, uint* __restrict__ P,
    int* __restrict__ deg) {
  int w = blockIdx.x * 256 + threadIdx.x;
  if (w >= WORDS) return;
  uint run = 0;
  if (P != nullptr) {
#pragma unroll 7
    for (int c = 0; c < NCHUNK; ++c) {
      uint v = partial[(size_t)c * WORDS + w];
      P[(size_t)c * WORDS + w] = run;
      run += v;
    }
  } else {
#pragma unroll 7
    for (int c = 0; c < NCHUNK; ++c) run += partial[(size_t)c * WORDS + w];
  }
  ((int4*)deg)[w] = make_int4(run & 0xff, (run >> 8) & 0xff,
                              (run >> 16) & 0xff, (run >> 24) & 0xff);
}

__global__ __launch_bounds__(256) void norm_kernel(
    const int* __restrict__ dout, const int* __restrict__ din,
    float* __restrict__ ns, float* __restrict__ nd, int n) {
  int i = blockIdx.x * 256 + threadIdx.x;
  if (i < n) {
    ns[i] = rsqrtf(fmaxf((float)dout[i], 1.0f));
    nd[i] = rsqrtf(fmaxf((float)din[i], 1.0f));
  }
}

// ---------------- exclusive scan (1024 elems / block) ----------------

__global__ __launch_bounds__(256) void scan1_kernel(
    const int* __restrict__ deg, int* __restrict__ row_off,
    int* __restrict__ bsums, int n) {
  __shared__ int s[256];
  int t = threadIdx.x;
  int base = blockIdx.x * 1024 + t * 4;
  int v0 = 0, v1 = 0, v2 = 0, v3 = 0;
  if (base + 0 < n) v0 = deg[base + 0];
  if (base + 1 < n) v1 = deg[base + 1];
  if (base + 2 < n) v2 = deg[base + 2];
  if (base + 3 < n) v3 = deg[base + 3];
  int sum = v0 + v1 + v2 + v3;
  s[t] = sum;
  __syncthreads();
  for (int off = 1; off < 256; off <<= 1) {
    int x = (t >= off) ? s[t - off] : 0;
    __syncthreads();
    s[t] += x;
    __syncthreads();
  }
  int excl = s[t] - sum;
  if (t == 255) bsums[blockIdx.x] = s[255];
  if (base + 0 < n) row_off[base + 0] = excl;
  if (base + 1 < n) row_off[base + 1] = excl + v0;
  if (base + 2 < n) row_off[base + 2] = excl + v0 + v1;
  if (base + 3 < n) row_off[base + 3] = excl + v0 + v1 + v2;
}

__global__ __launch_bounds__(128) void scan2_kernel(
    int* __restrict__ bsums, int nb, int* __restrict__ row_off, int n) {
  __shared__ int s[128];
  int t = threadIdx.x;
  int v = (t < nb) ? bsums[t] : 0;
  s[t] = v;
  __syncthreads();
  for (int off = 1; off < 128; off <<= 1) {
    int x = (t >= off) ? s[t - off] : 0;
    __syncthreads();
    s[t] += x;
    __syncthreads();
  }
  if (t < nb) bsums[t] = s[t] - v;
  if (t == 127) row_off[n] = s[127];
}

__global__ __launch_bounds__(256) void scan3_kernel(
    int* __restrict__ row_off, const int* __restrict__ bsums, int n) {
  int i = blockIdx.x * 256 + threadIdx.x;
  if (i < n) row_off[i] += bsums[i >> 10];
}

// ---------------- CSR fill (atomic-free) ----------------

__global__ __launch_bounds__(256) void fill_kernel(
    const int* __restrict__ src, const int* __restrict__ dst,
    const int* __restrict__ row_off, const unsigned char* __restrict__ Pb,
    const unsigned char* __restrict__ lrank, int* __restrict__ csr, int e) {
  int i = blockIdx.x * 256 + threadIdx.x;
  if (i < e) {
    int d = dst[i];
    int c = i >> CBITS;
    int pos = row_off[d] + (int)Pb[(size_t)c * NN + d] + (int)lrank[i];
    csr[pos] = src[i];
  }
}

// ---------------- bf16 helpers ----------------

__device__ __forceinline__ uint pack_bf16(float a, float b) {
  uint ua = __float_as_uint(a), ub = __float_as_uint(b);
  ua = (ua + 0x7fffu + ((ua >> 16) & 1u)) >> 16;          // RNE
  ub = (ub + 0x7fffu + ((ub >> 16) & 1u)) & 0xffff0000u;  // RNE
  return ua | ub;  // a -> low ushort (even idx), b -> high (odd idx)
}

__device__ __forceinline__ ushort to_bf16(float a) {
  uint ua = __float_as_uint(a);
  return (ushort)((ua + 0x7fffu + ((ua >> 16) & 1u)) >> 16);
}

union U16 {
  uint4 u;
  short8 s;
};
__device__ __forceinline__ short8 as_short8(uint4 u) {
  U16 t;
  t.u = u;
  return t.s;
}

__device__ __forceinline__ void acc8_add(float* acc, uint4 v) {
  acc[0] += __uint_as_float(v.x << 16);
  acc[1] += __uint_as_float(v.x & 0xffff0000u);
  acc[2] += __uint_as_float(v.y << 16);
  acc[3] += __uint_as_float(v.y & 0xffff0000u);
  acc[4] += __uint_as_float(v.z << 16);
  acc[5] += __uint_as_float(v.z & 0xffff0000u);
  acc[6] += __uint_as_float(v.w << 16);
  acc[7] += __uint_as_float(v.w & 0xffff0000u);
}

// ---------------- weight transpose + bf16 convert ----------------
// Wt1[n][k]=W1[k][n] (64x128), Wt2[n][k]=W2[k][n] (128x64), Wt3 like Wt1.

__global__ __launch_bounds__(256) void transw_kernel(
    const float* __restrict__ W1, const float* __restrict__ W2,
    const float* __restrict__ W3, ushort* __restrict__ Wt1,
    ushort* __restrict__ Wt2, ushort* __restrict__ Wt3) {
  int i = blockIdx.x * 256 + threadIdx.x;  // 0..24575
  if (i < 8192) {
    int n = i >> 7, k = i & 127;
    Wt1[i] = to_bf16(W1[k * 64 + n]);
  } else if (i < 16384) {
    int j = i - 8192;
    int n = j >> 6, k = j & 63;
    Wt2[j] = to_bf16(W2[k * 128 + n]);
  } else if (i < 24576) {
    int j = i - 16384;
    int n = j >> 7, k = j & 127;
    Wt3[j] = to_bf16(W3[k * 64 + n]);
  }
}

// ---------------- skinny MFMA GEMM: C = op(A @ W + bias) * scale ----------
// A: [n][K] (fp32 if AF32 else bf16), Wt: [N][K] bf16 (transposed), C: [n][N]
// bf16. Block = 4 waves x 16 rows = 64 rows. mfma_f32_16x16x32_bf16:
// A-frag A[m=lane&15][k=quad*8+j], B-frag B[n=lane&15][k=quad*8+j],
// C/D col=lane&15 (n), row=quad*4+reg (m)  [learn_hip m89/m120 verified].

template <int K, int N, bool AF32, bool RELU, bool BIAS, bool SCALE>
__global__ __launch_bounds__(256) void gemm_mfma_kernel(
    const void* __restrict__ Av, const ushort* __restrict__ Wt,
    const float* __restrict__ bias, const float* __restrict__ scale,
    ushort* __restrict__ C, int n) {
  int wid = threadIdx.x >> 6, lane = threadIdx.x & 63;
  int r = lane & 15, quad = lane >> 4;
  int m16 = blockIdx.x * 64 + wid * 16;
  if (m16 >= n) return;
  int mc = min(m16 + r, n - 1);
  constexpr int KS = K / 32;
  short8 a[KS];
  if (AF32) {
    const float* A = (const float*)Av;
#pragma unroll
    for (int ks = 0; ks < KS; ++ks) {
      const float4* p = (const float4*)(A + (size_t)mc * K + ks * 32 + quad * 8);
      float4 x = p[0], y = p[1];
      uint4 u;
      u.x = pack_bf16(x.x, x.y);
      u.y = pack_bf16(x.z, x.w);
      u.z = pack_bf16(y.x, y.y);
      u.w = pack_bf16(y.z, y.w);
      a[ks] = as_short8(u);
    }
  } else {
    const ushort* A = (const ushort*)Av;
#pragma unroll
    for (int ks = 0; ks < KS; ++ks)
      a[ks] = as_short8(*(const uint4*)(A + (size_t)mc * K + ks * 32 + quad * 8));
  }
#pragma unroll
  for (int nt = 0; nt < N / 16; ++nt) {
    f32x4 acc = {0.f, 0.f, 0.f, 0.f};
#pragma unroll
    for (int ks = 0; ks < KS; ++ks) {
      short8 b = as_short8(
          *(const uint4*)(Wt + (size_t)(nt * 16 + r) * K + ks * 32 + quad * 8));
      acc = __builtin_amdgcn_mfma_f32_16x16x32_bf16(a[ks], b, acc, 0, 0, 0);
    }
    float bv = 0.f;
    if (BIAS) bv = bias[nt * 16 + r];
#pragma unroll
    for (int reg = 0; reg < 4; ++reg) {
      int m = m16 + quad * 4 + reg;
      if (m < n) {
        float v = acc[reg] + bv;
        if (RELU) v = fmaxf(v, 0.f);
        if (SCALE) v *= scale[m];
        C[(size_t)m * N + nt * 16 + r] = to_bf16(v);
      }
    }
  }
}

// ---------------- 64-feature bf16 CSR gather ----------------
// 8 lanes per edge (lane = 8*eg + fl); lane loads uint4 = 8 bf16 features.
// One wave-load covers 8 edges. fp32 accumulate, shfl_xor butterfly.

__device__ __forceinline__ void gather64_bf16(const int* __restrict__ csr,
                                              const ushort* __restrict__ x,
                                              int rs, int re, int lane,
                                              float* acc) {
  const int eg = lane >> 3;
  const int fl = lane & 7;
  for (int e0 = rs; e0 < re; e0 += 64) {
    int idx = e0 + lane;
    int sv = (idx < re) ? csr[idx] : 0;
    int cnt = re - e0;
    if (cnt > 64) cnt = 64;
#pragma unroll
    for (int j = 0; j < 8; ++j) {
      int jb = j * 8;
      if (jb + 8 <= cnt) {  // full sub-batch (wave-uniform)
        int s = __shfl(sv, jb + eg);
        uint4 v = *(const uint4*)(x + (size_t)s * 64 + fl * 8);
        acc8_add(acc, v);
      } else if (jb < cnt) {  // partial sub-batch
        int s = __shfl(sv, jb + eg);
        uint m = (jb + eg < cnt) ? 0xffffffffu : 0u;
        uint4 v = *(const uint4*)(x + (size_t)s * 64 + fl * 8);
        v.x &= m; v.y &= m; v.z &= m; v.w &= m;
        acc8_add(acc, v);
      }
    }
  }
#pragma unroll
  for (int k = 0; k < 8; ++k) {
    acc[k] += __shfl_xor(acc[k], 8);
    acc[k] += __shfl_xor(acc[k], 16);
    acc[k] += __shfl_xor(acc[k], 32);
  }
}

// ---------------- layer 1 aggregate + epilogue (bf16 out) ----------------
// h1s[n][j] = bf16(relu(seg(t1)*nd + b1[j]) * ns[n])

__global__ __launch_bounds__(256) void agg1_kernel(
    const int* __restrict__ row_off, const int* __restrict__ csr,
    const ushort* __restrict__ t, const float* __restrict__ nd,
    const float* __restrict__ ns, const float* __restrict__ b,
    ushort* __restrict__ out, int n) {
  int wid = threadIdx.x >> 6, lane = threadIdx.x & 63;
  int node = blockIdx.x * 4 + wid;
  if (node >= n) return;
  float acc[8] = {0, 0, 0, 0, 0, 0, 0, 0};
  gather64_bf16(csr, t, row_off[node], row_off[node + 1], lane, acc);
  int fl = lane & 7;
  float ndv = nd[node], nsv = ns[node];
  const float4* bp = (const float4*)(b + fl * 8);
  float4 b0 = bp[0], b1v = bp[1];
  float o[8];
  o[0] = fmaxf(acc[0] * ndv + b0.x, 0.f) * nsv;
  o[1] = fmaxf(acc[1] * ndv + b0.y, 0.f) * nsv;
  o[2] = fmaxf(acc[2] * ndv + b0.z, 0.f) * nsv;
  o[3] = fmaxf(acc[3] * ndv + b0.w, 0.f) * nsv;
  o[4] = fmaxf(acc[4] * ndv + b1v.x, 0.f) * nsv;
  o[5] = fmaxf(acc[5] * ndv + b1v.y, 0.f) * nsv;
  o[6] = fmaxf(acc[6] * ndv + b1v.z, 0.f) * nsv;
  o[7] = fmaxf(acc[7] * ndv + b1v.w, 0.f) * nsv;
  if ((lane >> 3) == 0) {
    uint4 v;
    v.x = pack_bf16(o[0], o[1]);
    v.y = pack_bf16(o[2], o[3]);
    v.z = pack_bf16(o[4], o[5]);
    v.w = pack_bf16(o[6], o[7]);
    *(uint4*)(out + (size_t)node * 64 + fl * 8) = v;
  }
}

// ---------------- layer 2 aggregate (gather-only, bf16 out) ----------------
// m2[n][j] = bf16(seg(h1s)*nd)   (dense 64->128 moved to gemm_mfma)

__global__ __launch_bounds__(256) void agg2_kernel(
    const int* __restrict__ row_off, const int* __restrict__ csr,
    const ushort* __restrict__ h1s, const float* __restrict__ nd,
    ushort* __restrict__ m2, int n) {
  int wid = threadIdx.x >> 6, lane = threadIdx.x & 63;
  int node = blockIdx.x * 4 + wid;
  if (node >= n) return;
  float acc[8] = {0, 0, 0, 0, 0, 0, 0, 0};
  gather64_bf16(csr, h1s, row_off[node], row_off[node + 1], lane, acc);
  float ndv = nd[node];
  int fl = lane & 7;
  if ((lane >> 3) == 0) {
    uint4 v;
    v.x = pack_bf16(acc[0] * ndv, acc[1] * ndv);
    v.y = pack_bf16(acc[2] * ndv, acc[3] * ndv);
    v.z = pack_bf16(acc[4] * ndv, acc[5] * ndv);
    v.w = pack_bf16(acc[6] * ndv, acc[7] * ndv);
    *(uint4*)(m2 + (size_t)node * 64 + fl * 8) = v;
  }
}

// ---------------- layer 3 aggregate + block-reduced readout ----------------

__global__ __launch_bounds__(1024) void agg3_kernel(
    const int* __restrict__ row_off, const int* __restrict__ csr,
    const ushort* __restrict__ t, const float* __restrict__ nd,
    const float* __restrict__ b, const int* __restrict__ gid,
    float* __restrict__ hg, int n) {
  __shared__ float sO[16][64];
  __shared__ int sG[16];
  __shared__ int uni;
  int wid = threadIdx.x >> 6, lane = threadIdx.x & 63;
  int node = blockIdx.x * 16 + wid;  // NN % 16 == 0: always valid
  float acc[8] = {0, 0, 0, 0, 0, 0, 0, 0};
  gather64_bf16(csr, t, row_off[node], row_off[node + 1], lane, acc);
  int fl = lane & 7;
  float ndv = nd[node];
  const float4* bp = (const float4*)(b + fl * 8);
  float4 b0 = bp[0], b1v = bp[1];
  if ((lane >> 3) == 0) {
    sO[wid][fl * 8 + 0] = fmaxf(acc[0] * ndv + b0.x, 0.f);
    sO[wid][fl * 8 + 1] = fmaxf(acc[1] * ndv + b0.y, 0.f);
    sO[wid][fl * 8 + 2] = fmaxf(acc[2] * ndv + b0.z, 0.f);
    sO[wid][fl * 8 + 3] = fmaxf(acc[3] * ndv + b0.w, 0.f);
    sO[wid][fl * 8 + 4] = fmaxf(acc[4] * ndv + b1v.x, 0.f);
    sO[wid][fl * 8 + 5] = fmaxf(acc[5] * ndv + b1v.y, 0.f);
    sO[wid][fl * 8 + 6] = fmaxf(acc[6] * ndv + b1v.z, 0.f);
    sO[wid][fl * 8 + 7] = fmaxf(acc[7] * ndv + b1v.w, 0.f);
  }
  if (lane == 0) sG[wid] = gid[node];
  __syncthreads();
  if (threadIdx.x == 0) {
    int g0 = sG[0], u = 1;
#pragma unroll
    for (int i = 1; i < 16; ++i) u &= (sG[i] == g0);
    uni = u;
  }
  __syncthreads();
  if (uni) {
#pragma unroll
    for (int s = 8; s >= 1; s >>= 1) {
      if (wid < s) sO[wid][lane] += sO[wid + s][lane];
      __syncthreads();
    }
    if (threadIdx.x < 64) atomicAdd(&hg[sG[0] * 64 + lane], sO[0][lane]);
  } else {
    atomicAdd(&hg[sG[wid] * 64 + lane], sO[wid][lane]);
  }
}

// ---------------- readout dense ----------------

__global__ __launch_bounds__(640) void readout_kernel(
    const float* __restrict__ hg, const float* __restrict__ Wd,
    const float* __restrict__ bd, float* __restrict__ out) {
  int t = threadIdx.x;  // 640 = 64 graphs * 10 classes
  int g = t / 10, c = t % 10;
  float o = bd[c];
#pragma unroll 8
  for (int k = 0; k < 64; ++k) o += tanhf(hg[g * 64 + k]) * Wd[k * 10 + c];
  out[t] = o;
}

// ---------------- launch ----------------

extern "C" void kernel_launch(void* const* d_in, const int* in_sizes, int n_in,
                              void* d_out, int out_size, void* d_ws, size_t ws_size,
                              hipStream_t stream) {
  const float* in_feat = (const float*)d_in[0];
  const int* src = (const int*)d_in[1];
  const int* dst = (const int*)d_in[2];
  const int* gid = (const int*)d_in[3];
  const float* W1 = (const float*)d_in[4];
  const float* b1 = (const float*)d_in[5];
  const float* W2 = (const float*)d_in[6];
  const float* b2 = (const float*)d_in[7];
  const float* W3 = (const float*)d_in[8];
  const float* b3 = (const float*)d_in[9];
  const float* Wd = (const float*)d_in[10];
  const float* bd = (const float*)d_in[11];
  float* out = (float*)d_out;

  char* ws = (char*)d_ws;
  size_t o = 0;
  auto alloc = [&](size_t bytes) -> char* {
    char* p = ws + o;
    o = (o + bytes + 1023) & ~(size_t)1023;
    return p;
  };
  float* hg = (float*)alloc(NG * 64 * 4);
  size_t zero_bytes = o;  // only hg needs zero-init
  int* deg_out = (int*)alloc(NN * 4);
  int* deg_in = (int*)alloc(NN * 4);
  float* norm_src = (float*)alloc(NN * 4);
  float* norm_dst = (float*)alloc(NN * 4);
  int* row_off = (int*)alloc((NN + 1) * 4);
  int* bsums = (int*)alloc(512);
  ushort* Wt1 = (ushort*)alloc(64 * 128 * 2);
  ushort* Wt2 = (ushort*)alloc(128 * 64 * 2);
  ushort* Wt3 = (ushort*)alloc(64 * 128 * 2);
  int* csr = (int*)alloc((size_t)NE * 4);
  ushort* tbuf = (ushort*)alloc((size_t)NN * 64 * 2);  // bf16 t1, then t3
  ushort* h1s = (ushort*)alloc((size_t)NN * 64 * 2);   // bf16
  ushort* m2 = (ushort*)alloc((size_t)NN * 64 * 2);    // bf16 (12,800,000 B)
  ushort* h2s = (ushort*)alloc((size_t)NN * 128 * 2);  // bf16 (25,600,000 B)
  (void)ws_size;

  // overlays on the contiguous [m2, h2s) region (38.4MB; all overlay users
  // finish at fill_kernel, before m2/h2s are first written):
  char* ov = (char*)m2;
  uint* pdst = (uint*)ov;                              // 9.8MB
  uint* psrc = (uint*)(ov + 9800000);                  // 9.8MB
  uint* Pw = (uint*)(ov + 19600000);                   // 9.8MB
  unsigned char* lrank = (unsigned char*)(ov + 29400000);  // 3.2MB

  hipMemsetAsync(d_ws, 0, zero_bytes, stream);

  const int egrid = (NE + 255) / 256;     // 12500
  const int ngrid = (NN + 255) / 256;     // 391
  const int sgrid = (NN + 1023) / 1024;   // 98
  const int wgrid = (NN + 3) / 4;         // 25000 (wave-per-node)
  const int rgrid = (WORDS + 255) / 256;  // 98
  const int ggrid = (NN + 63) / 64;       // 1563 (gemm_mfma)

  transw_kernel<<<96, 256, 0, stream>>>(W1, W2, W3, Wt1, Wt2, Wt3);
  hist_kernel<<<dim3(NCHUNK, 2, 2), 1024, 0, stream>>>(src, dst, pdst, psrc, lrank);
  reduce_kernel<<<rgrid, 256, 0, stream>>>(pdst, Pw, deg_in);
  reduce_kernel<<<rgrid, 256, 0, stream>>>(psrc, nullptr, deg_out);
  norm_kernel<<<ngrid, 256, 0, stream>>>(deg_out, deg_in, norm_src, norm_dst, NN);
  scan1_kernel<<<sgrid, 256, 0, stream>>>(deg_in, row_off, bsums, NN);
  scan2_kernel<<<1, 128, 0, stream>>>(bsums, sgrid, row_off, NN);
  scan3_kernel<<<ngrid, 256, 0, stream>>>(row_off, bsums, NN);
  fill_kernel<<<egrid, 256, 0, stream>>>(src, dst, row_off,
                                         (const unsigned char*)Pw, lrank, csr, NE);

  // layer 1: t1 = bf16((in_feat @ W1) * ns)   [MFMA, fp32 A inline-converted]
  gemm_mfma_kernel<128, 64, true, false, false, true>
      <<<ggrid, 256, 0, stream>>>(in_feat, Wt1, nullptr, norm_src, tbuf, NN);
  // h1s = bf16(relu(seg(t1)*nd + b1) * ns)
  agg1_kernel<<<wgrid, 256, 0, stream>>>(row_off, csr, tbuf, norm_dst, norm_src,
                                         b1, h1s, NN);
  // m2 = bf16(seg(h1s)*nd)
  agg2_kernel<<<wgrid, 256, 0, stream>>>(row_off, csr, h1s, norm_dst, m2, NN);
  // h2s = bf16(relu(m2 @ W2 + b2) * ns)   [MFMA]
  gemm_mfma_kernel<64, 128, false, true, true, true>
      <<<ggrid, 256, 0, stream>>>(m2, Wt2, b2, norm_src, h2s, NN);
  // t3 = bf16(h2s @ W3)   [MFMA]
  gemm_mfma_kernel<128, 64, false, false, false, false>
      <<<ggrid, 256, 0, stream>>>(h2s, Wt3, nullptr, nullptr, tbuf, NN);
  // hg[g] += relu(seg(t3)*nd + b3)
  agg3_kernel<<<NN / 16, 1024, 0, stream>>>(row_off, csr, tbuf, norm_dst, b3,
                                            gid, hg, NN);
  readout_kernel<<<1, 640, 0, stream>>>(hg, Wd, bd, out);
}

// Round 6
// 472.212 us; speedup vs baseline: 3.4040x; 1.0516x over previous
//
#include <hip/hip_runtime.h>
#include <hip/hip_bf16.h>

// GCN: 3x GraphConv(norm='both') + graph readout + dense head.
// Strategy:
//  - ATOMIC-FREE CSR build (R2: device atomics cap at ~26G/s):
//      hist -> merged reduce (byte-lane sums + chunk-exclusive prefix) ->
//      scan -> fill (pos = row_off + P + lrank, no atomics).
//  - Algebra: transform-first for 128->64 layers so ALL gathers are 64-feat.
//  - bf16 features; 8 lanes/edge uint4 loads (R3); ALL dense multiplies are
//    MFMA 16x16x32 bf16 (R4).
//  - R5: aggs were MLP-starved (VALU 40%, mem 23%, occ 76% - nothing
//    saturated; ~1900cy fixed chain per node, ~4 loads in flight). Waves now
//    PAIR-GATHER 2 adjacent dst nodes over their combined contiguous csr
//    range: one row_off triple + shared index loads; j-groups routed to
//    acc0/acc1 by a wave-uniform boundary. float2 accs for v_pk_add_f32.
//  - agg3: block LDS-reduce 16 nodes -> ~1 atomic row/block.

constexpr int NN = 100000;   // nodes
constexpr int NE = 3200000;  // edges
constexpr int NG = 64;       // graphs

constexpr int CBITS = 15;
constexpr int CHUNK = 1 << CBITS;                 // 32768 edges/chunk
constexpr int NCHUNK = (NE + CHUNK - 1) / CHUNK;  // 98
constexpr int WORDS = NN / 4;                     // 25000 packed u8x4 words
constexpr int HWORDS = WORDS / 2;                 // 12500 (half node range)

typedef __attribute__((ext_vector_type(8))) short short8;
typedef __attribute__((ext_vector_type(4))) float f32x4;
typedef __attribute__((ext_vector_type(2))) float f32x2;

// ---------------- chunked LDS histogram ----------------

__global__ __launch_bounds__(1024) void hist_kernel(
    const int* __restrict__ src, const int* __restrict__ dst,
    uint* __restrict__ pdst, uint* __restrict__ psrc,
    unsigned char* __restrict__ lrank) {
  __shared__ uint bins[HWORDS];  // 50KB
  for (int i = threadIdx.x; i < HWORDS; i += 1024) bins[i] = 0;
  __syncthreads();
  const int c = blockIdx.x, r = blockIdx.z;
  const int nlo = r * (NN / 2), nhi = nlo + NN / 2;
  const int wbase = r * HWORDS;
  const int start = c << CBITS;
  const int end = min(start + CHUNK, NE);
  const int* idx = (blockIdx.y == 0) ? dst : src;
  if (blockIdx.y == 0) {
    for (int i = start + threadIdx.x; i < end; i += 1024) {
      int n = idx[i];
      if (n >= nlo && n < nhi) {
        uint old = atomicAdd(&bins[(n >> 2) - wbase], 1u << ((n & 3) * 8));
        lrank[i] = (unsigned char)(old >> ((n & 3) * 8));
      }
    }
  } else {
    for (int i = start + threadIdx.x; i < end; i += 1024) {
      int n = idx[i];
      if (n >= nlo && n < nhi)
        atomicAdd(&bins[(n >> 2) - wbase], 1u << ((n & 3) * 8));
    }
  }
  __syncthreads();
  uint* pp = ((blockIdx.y == 0) ? pdst : psrc) + (size_t)c * WORDS + wbase;
  for (int i = threadIdx.x; i < HWORDS; i += 1024) pp[i] = bins[i];
}

// ---------------- merged reduce: deg + chunk-exclusive prefix ----------------
// y==0: pdst -> (P, deg_in);  y==1: psrc -> deg_out.

__global__ __launch_bounds__(256) void reduce2_kernel(
    const uint* __restrict__ pdst, const uint* __restrict__ psrc,
    uint* __restrict__ P, int* __restrict__ deg_in,
    int* __restrict__ deg_out) {
  int w = blockIdx.x * 256 + threadIdx.x;
  if (w >= WORDS) return;
  uint run = 0;
  if (blockIdx.y == 0) {
#pragma unroll 7
    for (int c = 0; c < NCHUNK; ++c) {
      uint v = pdst[(size_t)c * WORDS + w];
      P[(size_t)c * WORDS + w] = run;
      run += v;
    }
    ((int4*)deg_in)[w] = make_int4(run & 0xff, (run >> 8) & 0xff,
                                   (run >> 16) & 0xff, (run >> 24) & 0xff);
  } else {
#pragma unroll 7
    for (int c = 0; c < NCHUNK; ++c) run += psrc[(size_t)c * WORDS + w];
    ((int4*)deg_out)[w] = make_int4(run & 0xff, (run >> 8) & 0xff,
                                    (run >> 16) & 0xff, (run >> 24) & 0xff);
  }
}

__global__ __launch_bounds__(256) void norm_kernel(
    const int* __restrict__ dout, const int* __restrict__ din,
    float* __restrict__ ns, float* __restrict__ nd, int n) {
  int i = blockIdx.x * 256 + threadIdx.x;
  if (i < n) {
    ns[i] = rsqrtf(fmaxf((float)dout[i], 1.0f));
    nd[i] = rsqrtf(fmaxf((float)din[i], 1.0f));
  }
}

// ---------------- exclusive scan (1024 elems / block) ----------------

__global__ __launch_bounds__(256) void scan1_kernel(
    const int* __restrict__ deg, int* __restrict__ row_off,
    int* __restrict__ bsums, int n) {
  __shared__ int s[256];
  int t = threadIdx.x;
  int base = blockIdx.x * 1024 + t * 4;
  int v0 = 0, v1 = 0, v2 = 0, v3 = 0;
  if (base + 0 < n) v0 = deg[base + 0];
  if (base + 1 < n) v1 = deg[base + 1];
  if (base + 2 < n) v2 = deg[base + 2];
  if (base + 3 < n) v3 = deg[base + 3];
  int sum = v0 + v1 + v2 + v3;
  s[t] = sum;
  __syncthreads();
  for (int off = 1; off < 256; off <<= 1) {
    int x = (t >= off) ? s[t - off] : 0;
    __syncthreads();
    s[t] += x;
    __syncthreads();
  }
  int excl = s[t] - sum;
  if (t == 255) bsums[blockIdx.x] = s[255];
  if (base + 0 < n) row_off[base + 0] = excl;
  if (base + 1 < n) row_off[base + 1] = excl + v0;
  if (base + 2 < n) row_off[base + 2] = excl + v0 + v1;
  if (base + 3 < n) row_off[base + 3] = excl + v0 + v1 + v2;
}

__global__ __launch_bounds__(128) void scan2_kernel(
    int* __restrict__ bsums, int nb, int* __restrict__ row_off, int n) {
  __shared__ int s[128];
  int t = threadIdx.x;
  int v = (t < nb) ? bsums[t] : 0;
  s[t] = v;
  __syncthreads();
  for (int off = 1; off < 128; off <<= 1) {
    int x = (t >= off) ? s[t - off] : 0;
    __syncthreads();
    s[t] += x;
    __syncthreads();
  }
  if (t < nb) bsums[t] = s[t] - v;
  if (t == 127) row_off[n] = s[127];
}

__global__ __launch_bounds__(256) void scan3_kernel(
    int* __restrict__ row_off, const int* __restrict__ bsums, int n) {
  int i = blockIdx.x * 256 + threadIdx.x;
  if (i < n) row_off[i] += bsums[i >> 10];
}

// ---------------- CSR fill (atomic-free) ----------------

__global__ __launch_bounds__(256) void fill_kernel(
    const int* __restrict__ src, const int* __restrict__ dst,
    const int* __restrict__ row_off, const unsigned char* __restrict__ Pb,
    const unsigned char* __restrict__ lrank, int* __restrict__ csr, int e) {
  int i = blockIdx.x * 256 + threadIdx.x;
  if (i < e) {
    int d = dst[i];
    int c = i >> CBITS;
    int pos = row_off[d] + (int)Pb[(size_t)c * NN + d] + (int)lrank[i];
    csr[pos] = src[i];
  }
}

// ---------------- bf16 helpers ----------------

__device__ __forceinline__ uint pack_bf16(float a, float b) {
  uint ua = __float_as_uint(a), ub = __float_as_uint(b);
  ua = (ua + 0x7fffu + ((ua >> 16) & 1u)) >> 16;          // RNE
  ub = (ub + 0x7fffu + ((ub >> 16) & 1u)) & 0xffff0000u;  // RNE
  return ua | ub;  // a -> low ushort (even idx), b -> high (odd idx)
}

__device__ __forceinline__ ushort to_bf16(float a) {
  uint ua = __float_as_uint(a);
  return (ushort)((ua + 0x7fffu + ((ua >> 16) & 1u)) >> 16);
}

union U16 {
  uint4 u;
  short8 s;
};
__device__ __forceinline__ short8 as_short8(uint4 u) {
  U16 t;
  t.u = u;
  return t.s;
}

__device__ __forceinline__ f32x2 bf2(uint u) {
  f32x2 r;
  r.x = __uint_as_float(u << 16);
  r.y = __uint_as_float(u & 0xffff0000u);
  return r;
}

__device__ __forceinline__ void add8(f32x2* a, uint4 v) {
  a[0] += bf2(v.x);
  a[1] += bf2(v.y);
  a[2] += bf2(v.z);
  a[3] += bf2(v.w);
}

// ---------------- weight transpose + bf16 convert ----------------

__global__ __launch_bounds__(256) void transw_kernel(
    const float* __restrict__ W1, const float* __restrict__ W2,
    const float* __restrict__ W3, ushort* __restrict__ Wt1,
    ushort* __restrict__ Wt2, ushort* __restrict__ Wt3) {
  int i = blockIdx.x * 256 + threadIdx.x;  // 0..24575
  if (i < 8192) {
    int n = i >> 7, k = i & 127;
    Wt1[i] = to_bf16(W1[k * 64 + n]);
  } else if (i < 16384) {
    int j = i - 8192;
    int n = j >> 6, k = j & 63;
    Wt2[j] = to_bf16(W2[k * 128 + n]);
  } else if (i < 24576) {
    int j = i - 16384;
    int n = j >> 7, k = j & 127;
    Wt3[j] = to_bf16(W3[k * 64 + n]);
  }
}

// ---------------- skinny MFMA GEMM: C = op(A @ W + bias) * scale ----------
// A: [n][K] (fp32 if AF32 else bf16), Wt: [N][K] bf16 (transposed), C: [n][N]
// bf16. Block = 4 waves x 16 rows. mfma_f32_16x16x32_bf16:
// A-frag A[m=lane&15][k=quad*8+j], C/D col=lane&15, row=quad*4+reg.

template <int K, int N, bool AF32, bool RELU, bool BIAS, bool SCALE>
__global__ __launch_bounds__(256) void gemm_mfma_kernel(
    const void* __restrict__ Av, const ushort* __restrict__ Wt,
    const float* __restrict__ bias, const float* __restrict__ scale,
    ushort* __restrict__ C, int n) {
  int wid = threadIdx.x >> 6, lane = threadIdx.x & 63;
  int r = lane & 15, quad = lane >> 4;
  int m16 = blockIdx.x * 64 + wid * 16;
  if (m16 >= n) return;
  int mc = min(m16 + r, n - 1);
  constexpr int KS = K / 32;
  short8 a[KS];
  if (AF32) {
    const float* A = (const float*)Av;
#pragma unroll
    for (int ks = 0; ks < KS; ++ks) {
      const float4* p = (const float4*)(A + (size_t)mc * K + ks * 32 + quad * 8);
      float4 x = p[0], y = p[1];
      uint4 u;
      u.x = pack_bf16(x.x, x.y);
      u.y = pack_bf16(x.z, x.w);
      u.z = pack_bf16(y.x, y.y);
      u.w = pack_bf16(y.z, y.w);
      a[ks] = as_short8(u);
    }
  } else {
    const ushort* A = (const ushort*)Av;
#pragma unroll
    for (int ks = 0; ks < KS; ++ks)
      a[ks] = as_short8(*(const uint4*)(A + (size_t)mc * K + ks * 32 + quad * 8));
  }
#pragma unroll
  for (int nt = 0; nt < N / 16; ++nt) {
    f32x4 acc = {0.f, 0.f, 0.f, 0.f};
#pragma unroll
    for (int ks = 0; ks < KS; ++ks) {
      short8 b = as_short8(
          *(const uint4*)(Wt + (size_t)(nt * 16 + r) * K + ks * 32 + quad * 8));
      acc = __builtin_amdgcn_mfma_f32_16x16x32_bf16(a[ks], b, acc, 0, 0, 0);
    }
    float bv = 0.f;
    if (BIAS) bv = bias[nt * 16 + r];
#pragma unroll
    for (int reg = 0; reg < 4; ++reg) {
      int m = m16 + quad * 4 + reg;
      if (m < n) {
        float v = acc[reg] + bv;
        if (RELU) v = fmaxf(v, 0.f);
        if (SCALE) v *= scale[m];
        C[(size_t)m * N + nt * 16 + r] = to_bf16(v);
      }
    }
  }
}

// ---------------- paired 64-feature bf16 CSR gather ----------------
// One wave gathers TWO adjacent dst rows over the combined contiguous csr
// range [rs, re), boundary rm. 8 lanes/edge, uint4 = 8 bf16 features/lane.
// j-groups of 8 edges route to acc0/acc1 by the wave-uniform boundary
// c0 = rm - e0; only the straddling group pays a mask split. Butterfly at
// the end leaves every lane with both nodes' 8-feature totals.

__device__ __forceinline__ void gather2_bf16(const int* __restrict__ csr,
                                             const ushort* __restrict__ x,
                                             int rs, int rm, int re, int lane,
                                             f32x2* a0, f32x2* a1) {
  const int eg = lane >> 3;
  const int fl = lane & 7;
  for (int e0 = rs; e0 < re; e0 += 64) {
    int idx = e0 + lane;
    int sv = (idx < re) ? csr[idx] : 0;
    int cnt = re - e0;
    if (cnt > 64) cnt = 64;
    int c0 = rm - e0;  // slots < c0 belong to node0
#pragma unroll
    for (int j = 0; j < 8; ++j) {
      int jb = j * 8;
      if (jb < cnt) {  // wave-uniform
        int s = __shfl(sv, jb + eg);
        uint4 v = *(const uint4*)(x + (size_t)s * 64 + fl * 8);
        if (jb + 8 > cnt) {  // partial tail: mask invalid edge-groups
          uint mv = ((jb + eg) < cnt) ? 0xffffffffu : 0u;
          v.x &= mv; v.y &= mv; v.z &= mv; v.w &= mv;
        }
        if (jb + 8 <= c0) {
          add8(a0, v);
        } else if (jb >= c0) {
          add8(a1, v);
        } else {  // straddles the node boundary
          uint m0 = ((jb + eg) < c0) ? 0xffffffffu : 0u;
          uint4 v0;
          v0.x = v.x & m0; v0.y = v.y & m0; v0.z = v.z & m0; v0.w = v.w & m0;
          add8(a0, v0);
          v.x ^= v0.x; v.y ^= v0.y; v.z ^= v0.z; v.w ^= v0.w;
          add8(a1, v);
        }
      }
    }
  }
#pragma unroll
  for (int k = 0; k < 4; ++k) {
    a0[k].x += __shfl_xor(a0[k].x, 8);
    a0[k].x += __shfl_xor(a0[k].x, 16);
    a0[k].x += __shfl_xor(a0[k].x, 32);
    a0[k].y += __shfl_xor(a0[k].y, 8);
    a0[k].y += __shfl_xor(a0[k].y, 16);
    a0[k].y += __shfl_xor(a0[k].y, 32);
    a1[k].x += __shfl_xor(a1[k].x, 8);
    a1[k].x += __shfl_xor(a1[k].x, 16);
    a1[k].x += __shfl_xor(a1[k].x, 32);
    a1[k].y += __shfl_xor(a1[k].y, 8);
    a1[k].y += __shfl_xor(a1[k].y, 16);
    a1[k].y += __shfl_xor(a1[k].y, 32);
  }
}

// select feature k (0..7) of the proper node's accumulator
#define ACC_SEL(k) ((eg == 0) ? a0[(k) >> 1][(k)&1] : a1[(k) >> 1][(k)&1])

// ---------------- layer 1 aggregate + epilogue (bf16 out) ----------------
// h1s[n][j] = bf16(relu(seg(t1)*nd + b1[j]) * ns[n]); 2 nodes/wave.

__global__ __launch_bounds__(256) void agg1_kernel(
    const int* __restrict__ row_off, const int* __restrict__ csr,
    const ushort* __restrict__ t, const float* __restrict__ nd,
    const float* __restrict__ ns, const float* __restrict__ b,
    ushort* __restrict__ out, int n) {
  int wid = threadIdx.x >> 6, lane = threadIdx.x & 63;
  int n0 = blockIdx.x * 8 + wid * 2;  // n % 8 == 0
  int rs = row_off[n0], rm = row_off[n0 + 1], re = row_off[n0 + 2];
  f32x2 a0[4] = {{0, 0}, {0, 0}, {0, 0}, {0, 0}};
  f32x2 a1[4] = {{0, 0}, {0, 0}, {0, 0}, {0, 0}};
  gather2_bf16(csr, t, rs, rm, re, lane, a0, a1);
  int eg = lane >> 3, fl = lane & 7;
  if (eg < 2) {  // eg==0 -> node0, eg==1 -> node1
    int node = n0 + eg;
    float ndv = nd[node], nsv = ns[node];
    const float4* bp = (const float4*)(b + fl * 8);
    float4 b0 = bp[0], b1v = bp[1];
    float o0 = fmaxf(ACC_SEL(0) * ndv + b0.x, 0.f) * nsv;
    float o1 = fmaxf(ACC_SEL(1) * ndv + b0.y, 0.f) * nsv;
    float o2 = fmaxf(ACC_SEL(2) * ndv + b0.z, 0.f) * nsv;
    float o3 = fmaxf(ACC_SEL(3) * ndv + b0.w, 0.f) * nsv;
    float o4 = fmaxf(ACC_SEL(4) * ndv + b1v.x, 0.f) * nsv;
    float o5 = fmaxf(ACC_SEL(5) * ndv + b1v.y, 0.f) * nsv;
    float o6 = fmaxf(ACC_SEL(6) * ndv + b1v.z, 0.f) * nsv;
    float o7 = fmaxf(ACC_SEL(7) * ndv + b1v.w, 0.f) * nsv;
    uint4 v;
    v.x = pack_bf16(o0, o1);
    v.y = pack_bf16(o2, o3);
    v.z = pack_bf16(o4, o5);
    v.w = pack_bf16(o6, o7);
    *(uint4*)(out + (size_t)node * 64 + fl * 8) = v;
  }
}

// ---------------- layer 2 aggregate (gather-only, bf16 out) ----------------
// m2[n][j] = bf16(seg(h1s)*nd); 2 nodes/wave.

__global__ __launch_bounds__(256) void agg2_kernel(
    const int* __restrict__ row_off, const int* __restrict__ csr,
    const ushort* __restrict__ h1s, const float* __restrict__ nd,
    ushort* __restrict__ m2, int n) {
  int wid = threadIdx.x >> 6, lane = threadIdx.x & 63;
  int n0 = blockIdx.x * 8 + wid * 2;
  int rs = row_off[n0], rm = row_off[n0 + 1], re = row_off[n0 + 2];
  f32x2 a0[4] = {{0, 0}, {0, 0}, {0, 0}, {0, 0}};
  f32x2 a1[4] = {{0, 0}, {0, 0}, {0, 0}, {0, 0}};
  gather2_bf16(csr, h1s, rs, rm, re, lane, a0, a1);
  int eg = lane >> 3, fl = lane & 7;
  if (eg < 2) {
    int node = n0 + eg;
    float ndv = nd[node];
    uint4 v;
    v.x = pack_bf16(ACC_SEL(0) * ndv, ACC_SEL(1) * ndv);
    v.y = pack_bf16(ACC_SEL(2) * ndv, ACC_SEL(3) * ndv);
    v.z = pack_bf16(ACC_SEL(4) * ndv, ACC_SEL(5) * ndv);
    v.w = pack_bf16(ACC_SEL(6) * ndv, ACC_SEL(7) * ndv);
    *(uint4*)(m2 + (size_t)node * 64 + fl * 8) = v;
  }
}

// ---------------- layer 3 aggregate + block-reduced readout ----------------
// 512 threads = 8 waves x 2 nodes = 16 nodes/block; LDS tree-reduce ->
// ~1 atomic row per block (gids sorted: nearly all blocks gid-uniform).

__global__ __launch_bounds__(512) void agg3_kernel(
    const int* __restrict__ row_off, const int* __restrict__ csr,
    const ushort* __restrict__ t, const float* __restrict__ nd,
    const float* __restrict__ b, const int* __restrict__ gid,
    float* __restrict__ hg, int n) {
  __shared__ float sO[16][64];
  __shared__ int sG[16];
  __shared__ int uni;
  int wid = threadIdx.x >> 6, lane = threadIdx.x & 63;
  int n0 = blockIdx.x * 16 + wid * 2;  // NN % 16 == 0
  int rs = row_off[n0], rm = row_off[n0 + 1], re = row_off[n0 + 2];
  f32x2 a0[4] = {{0, 0}, {0, 0}, {0, 0}, {0, 0}};
  f32x2 a1[4] = {{0, 0}, {0, 0}, {0, 0}, {0, 0}};
  gather2_bf16(csr, t, rs, rm, re, lane, a0, a1);
  int eg = lane >> 3, fl = lane & 7;
  if (eg < 2) {
    int node = n0 + eg;
    int row = wid * 2 + eg;
    float ndv = nd[node];
    const float4* bp = (const float4*)(b + fl * 8);
    float4 b0 = bp[0], b1v = bp[1];
    sO[row][fl * 8 + 0] = fmaxf(ACC_SEL(0) * ndv + b0.x, 0.f);
    sO[row][fl * 8 + 1] = fmaxf(ACC_SEL(1) * ndv + b0.y, 0.f);
    sO[row][fl * 8 + 2] = fmaxf(ACC_SEL(2) * ndv + b0.z, 0.f);
    sO[row][fl * 8 + 3] = fmaxf(ACC_SEL(3) * ndv + b0.w, 0.f);
    sO[row][fl * 8 + 4] = fmaxf(ACC_SEL(4) * ndv + b1v.x, 0.f);
    sO[row][fl * 8 + 5] = fmaxf(ACC_SEL(5) * ndv + b1v.y, 0.f);
    sO[row][fl * 8 + 6] = fmaxf(ACC_SEL(6) * ndv + b1v.z, 0.f);
    sO[row][fl * 8 + 7] = fmaxf(ACC_SEL(7) * ndv + b1v.w, 0.f);
  }
  if (lane == 0) sG[wid * 2] = gid[n0];
  if (lane == 8) sG[wid * 2 + 1] = gid[n0 + 1];
  __syncthreads();
  if (threadIdx.x == 0) {
    int g0 = sG[0], u = 1;
#pragma unroll
    for (int i = 1; i < 16; ++i) u &= (sG[i] == g0);
    uni = u;
  }
  __syncthreads();
  if (uni) {
    int r = threadIdx.x >> 6;  // 0..7
#pragma unroll
    for (int s = 8; s >= 1; s >>= 1) {
      if (r < s) sO[r][lane] += sO[r + s][lane];
      __syncthreads();
    }
    if (threadIdx.x < 64) atomicAdd(&hg[sG[0] * 64 + lane], sO[0][lane]);
  } else {
    atomicAdd(&hg[sG[wid * 2] * 64 + lane], sO[wid * 2][lane]);
    atomicAdd(&hg[sG[wid * 2 + 1] * 64 + lane], sO[wid * 2 + 1][lane]);
  }
}

// ---------------- readout dense ----------------

__global__ __launch_bounds__(640) void readout_kernel(
    const float* __restrict__ hg, const float* __restrict__ Wd,
    const float* __restrict__ bd, float* __restrict__ out) {
  int t = threadIdx.x;  // 640 = 64 graphs * 10 classes
  int g = t / 10, c = t % 10;
  float o = bd[c];
#pragma unroll 8
  for (int k = 0; k < 64; ++k) o += tanhf(hg[g * 64 + k]) * Wd[k * 10 + c];
  out[t] = o;
}

// ---------------- launch ----------------

extern "C" void kernel_launch(void* const* d_in, const int* in_sizes, int n_in,
                              void* d_out, int out_size, void* d_ws, size_t ws_size,
                              hipStream_t stream) {
  const float* in_feat = (const float*)d_in[0];
  const int* src = (const int*)d_in[1];
  const int* dst = (const int*)d_in[2];
  const int* gid = (const int*)d_in[3];
  const float* W1 = (const float*)d_in[4];
  const float* b1 = (const float*)d_in[5];
  const float* W2 = (const float*)d_in[6];
  const float* b2 = (const float*)d_in[7];
  const float* W3 = (const float*)d_in[8];
  const float* b3 = (const float*)d_in[9];
  const float* Wd = (const float*)d_in[10];
  const float* bd = (const float*)d_in[11];
  float* out = (float*)d_out;

  char* ws = (char*)d_ws;
  size_t o = 0;
  auto alloc = [&](size_t bytes) -> char* {
    char* p = ws + o;
    o = (o + bytes + 1023) & ~(size_t)1023;
    return p;
  };
  float* hg = (float*)alloc(NG * 64 * 4);
  size_t zero_bytes = o;  // only hg needs zero-init
  int* deg_out = (int*)alloc(NN * 4);
  int* deg_in = (int*)alloc(NN * 4);
  float* norm_src = (float*)alloc(NN * 4);
  float* norm_dst = (float*)alloc(NN * 4);
  int* row_off = (int*)alloc((NN + 1) * 4);
  int* bsums = (int*)alloc(512);
  ushort* Wt1 = (ushort*)alloc(64 * 128 * 2);
  ushort* Wt2 = (ushort*)alloc(128 * 64 * 2);
  ushort* Wt3 = (ushort*)alloc(64 * 128 * 2);
  int* csr = (int*)alloc((size_t)NE * 4);
  ushort* tbuf = (ushort*)alloc((size_t)NN * 64 * 2);  // bf16 t1, then t3
  ushort* h1s = (ushort*)alloc((size_t)NN * 64 * 2);   // bf16
  ushort* m2 = (ushort*)alloc((size_t)NN * 64 * 2);    // bf16 (12,800,000 B)
  ushort* h2s = (ushort*)alloc((size_t)NN * 128 * 2);  // bf16 (25,600,000 B)
  (void)ws_size;

  // overlays on the contiguous [m2, h2s) region (38.4MB; all overlay users
  // finish at fill_kernel, before m2/h2s are first written):
  char* ov = (char*)m2;
  uint* pdst = (uint*)ov;                                  // 9.8MB
  uint* psrc = (uint*)(ov + 9800000);                      // 9.8MB
  uint* Pw = (uint*)(ov + 19600000);                       // 9.8MB
  unsigned char* lrank = (unsigned char*)(ov + 29400000);  // 3.2MB

  hipMemsetAsync(d_ws, 0, zero_bytes, stream);

  const int egrid = (NE + 255) / 256;     // 12500
  const int ngrid = (NN + 255) / 256;     // 391
  const int sgrid = (NN + 1023) / 1024;   // 98
  const int wgrid2 = NN / 8;              // 12500 (pair-gather, 4 waves/blk)
  const int rgrid = (WORDS + 255) / 256;  // 98
  const int ggrid = (NN + 63) / 64;       // 1563 (gemm_mfma)

  transw_kernel<<<96, 256, 0, stream>>>(W1, W2, W3, Wt1, Wt2, Wt3);
  hist_kernel<<<dim3(NCHUNK, 2, 2), 1024, 0, stream>>>(src, dst, pdst, psrc, lrank);
  reduce2_kernel<<<dim3(rgrid, 2), 256, 0, stream>>>(pdst, psrc, Pw, deg_in,
                                                     deg_out);
  norm_kernel<<<ngrid, 256, 0, stream>>>(deg_out, deg_in, norm_src, norm_dst, NN);
  scan1_kernel<<<sgrid, 256, 0, stream>>>(deg_in, row_off, bsums, NN);
  scan2_kernel<<<1, 128, 0, stream>>>(bsums, sgrid, row_off, NN);
  scan3_kernel<<<ngrid, 256, 0, stream>>>(row_off, bsums, NN);
  fill_kernel<<<egrid, 256, 0, stream>>>(src, dst, row_off,
                                         (const unsigned char*)Pw, lrank, csr, NE);

  // layer 1: t1 = bf16((in_feat @ W1) * ns)   [MFMA, fp32 A inline-converted]
  gemm_mfma_kernel<128, 64, true, false, false, true>
      <<<ggrid, 256, 0, stream>>>(in_feat, Wt1, nullptr, norm_src, tbuf, NN);
  // h1s = bf16(relu(seg(t1)*nd + b1) * ns)
  agg1_kernel<<<wgrid2, 256, 0, stream>>>(row_off, csr, tbuf, norm_dst,
                                          norm_src, b1, h1s, NN);
  // m2 = bf16(seg(h1s)*nd)
  agg2_kernel<<<wgrid2, 256, 0, stream>>>(row_off, csr, h1s, norm_dst, m2, NN);
  // h2s = bf16(relu(m2 @ W2 + b2) * ns)   [MFMA]
  gemm_mfma_kernel<64, 128, false, true, true, true>
      <<<ggrid, 256, 0, stream>>>(m2, Wt2, b2, norm_src, h2s, NN);
  // t3 = bf16(h2s @ W3)   [MFMA]
  gemm_mfma_kernel<128, 64, false, false, false, false>
      <<<ggrid, 256, 0, stream>>>(h2s, Wt3, nullptr, nullptr, tbuf, NN);
  // hg[g] += relu(seg(t3)*nd + b3)
  agg3_kernel<<<NN / 16, 512, 0, stream>>>(row_off, csr, tbuf, norm_dst, b3,
                                           gid, hg, NN);
  readout_kernel<<<1, 640, 0, stream>>>(hg, Wd, bd, out);
}

// Round 7
// 457.127 us; speedup vs baseline: 3.5164x; 1.0330x over previous
//
#include <hip/hip_runtime.h>
#include <hip/hip_bf16.h>

// GCN: 3x GraphConv(norm='both') + graph readout + dense head.
// Strategy:
//  - ATOMIC-FREE CSR build (R2: device atomics cap ~26G/s):
//      hist (R6: 4-bit packed full-range LDS bins, single pass/array,
//      CBITS=16) -> reduce2 (nibble sums + FUSED norms) -> scan -> fill.
//  - Algebra: transform-first for 128->64 layers so ALL gathers are 64-feat.
//  - bf16 features; 8 lanes/edge uint4 loads (R3); ALL dense multiplies are
//    MFMA 16x16x32 bf16 (R4); gemm2+gemm3 fused via LDS tile (R6).
//  - R5: waves pair-gather 2 adjacent dst nodes over combined csr range.
//    Gather floor ~5.6 TB/s effective on 3x410MB random 128B reads.
//  - agg3: block LDS-reduce 16 nodes -> ~1 atomic row/block.

constexpr int NN = 100000;   // nodes
constexpr int NE = 3200000;  // edges
constexpr int NG = 64;       // graphs

constexpr int CBITS = 16;
constexpr int CHUNK = 1 << CBITS;                 // 65536 edges/chunk
constexpr int NCHUNK = (NE + CHUNK - 1) / CHUNK;  // 49
constexpr int WORDS4 = NN / 8;                    // 12500 packed u4x8 words

typedef __attribute__((ext_vector_type(8))) short short8;
typedef __attribute__((ext_vector_type(4))) float f32x4;
typedef __attribute__((ext_vector_type(2))) float f32x2;

// ---------------- chunked LDS histogram (4-bit bins, full node range) -----
// Per-chunk-per-node counts <=15 (Poisson(0.65); overflow P ~ 1e-9). y picks
// dst (also records local rank from the LDS-atomic return) or src.

__global__ __launch_bounds__(1024) void hist_kernel(
    const int* __restrict__ src, const int* __restrict__ dst,
    uint* __restrict__ pdst, uint* __restrict__ psrc,
    unsigned char* __restrict__ lrank) {
  __shared__ uint bins[WORDS4];  // 50KB
  for (int i = threadIdx.x; i < WORDS4; i += 1024) bins[i] = 0;
  __syncthreads();
  const int c = blockIdx.x;
  const int start = c << CBITS;
  const int end = min(start + CHUNK, NE);
  if (blockIdx.y == 0) {
    for (int i = start + threadIdx.x; i < end; i += 1024) {
      int n = dst[i];
      uint old = atomicAdd(&bins[n >> 3], 1u << ((n & 7) * 4));
      lrank[i] = (unsigned char)((old >> ((n & 7) * 4)) & 0xf);
    }
  } else {
    for (int i = start + threadIdx.x; i < end; i += 1024) {
      int n = src[i];
      atomicAdd(&bins[n >> 3], 1u << ((n & 7) * 4));
    }
  }
  __syncthreads();
  uint* pp = ((blockIdx.y == 0) ? pdst : psrc) + (size_t)c * WORDS4;
  for (int i = threadIdx.x; i < WORDS4; i += 1024) pp[i] = bins[i];
}

// ------- reduce2: nibble sums -> deg_in + chunk-exclusive prefix + norms ---
// y==0: pdst -> (P bytes, deg_in, nd);  y==1: psrc -> ns.

__global__ __launch_bounds__(256) void reduce2_kernel(
    const uint* __restrict__ pdst, const uint* __restrict__ psrc,
    unsigned char* __restrict__ Pb, int* __restrict__ deg_in,
    float* __restrict__ nd, float* __restrict__ ns) {
  int w = blockIdx.x * 256 + threadIdx.x;
  if (w >= WORDS4) return;
  uint run[8] = {0, 0, 0, 0, 0, 0, 0, 0};
  if (blockIdx.y == 0) {
#pragma unroll 7
    for (int c = 0; c < NCHUNK; ++c) {
      uint lo = run[0] | (run[1] << 8) | (run[2] << 16) | (run[3] << 24);
      uint hi = run[4] | (run[5] << 8) | (run[6] << 16) | (run[7] << 24);
      ((uint2*)(Pb + (size_t)c * NN))[w] = make_uint2(lo, hi);
      uint v = pdst[(size_t)c * WORDS4 + w];
#pragma unroll
      for (int k = 0; k < 8; ++k) run[k] += (v >> (4 * k)) & 0xfu;
    }
    ((int4*)deg_in)[2 * w] =
        make_int4(run[0], run[1], run[2], run[3]);
    ((int4*)deg_in)[2 * w + 1] =
        make_int4(run[4], run[5], run[6], run[7]);
    float4 f0, f1;
    f0.x = rsqrtf(fmaxf((float)run[0], 1.f));
    f0.y = rsqrtf(fmaxf((float)run[1], 1.f));
    f0.z = rsqrtf(fmaxf((float)run[2], 1.f));
    f0.w = rsqrtf(fmaxf((float)run[3], 1.f));
    f1.x = rsqrtf(fmaxf((float)run[4], 1.f));
    f1.y = rsqrtf(fmaxf((float)run[5], 1.f));
    f1.z = rsqrtf(fmaxf((float)run[6], 1.f));
    f1.w = rsqrtf(fmaxf((float)run[7], 1.f));
    ((float4*)nd)[2 * w] = f0;
    ((float4*)nd)[2 * w + 1] = f1;
  } else {
#pragma unroll 7
    for (int c = 0; c < NCHUNK; ++c) {
      uint v = psrc[(size_t)c * WORDS4 + w];
#pragma unroll
      for (int k = 0; k < 8; ++k) run[k] += (v >> (4 * k)) & 0xfu;
    }
    float4 f0, f1;
    f0.x = rsqrtf(fmaxf((float)run[0], 1.f));
    f0.y = rsqrtf(fmaxf((float)run[1], 1.f));
    f0.z = rsqrtf(fmaxf((float)run[2], 1.f));
    f0.w = rsqrtf(fmaxf((float)run[3], 1.f));
    f1.x = rsqrtf(fmaxf((float)run[4], 1.f));
    f1.y = rsqrtf(fmaxf((float)run[5], 1.f));
    f1.z = rsqrtf(fmaxf((float)run[6], 1.f));
    f1.w = rsqrtf(fmaxf((float)run[7], 1.f));
    ((float4*)ns)[2 * w] = f0;
    ((float4*)ns)[2 * w + 1] = f1;
  }
}

// ---------------- exclusive scan (1024 elems / block) ----------------

__global__ __launch_bounds__(256) void scan1_kernel(
    const int* __restrict__ deg, int* __restrict__ row_off,
    int* __restrict__ bsums, int n) {
  __shared__ int s[256];
  int t = threadIdx.x;
  int base = blockIdx.x * 1024 + t * 4;
  int v0 = 0, v1 = 0, v2 = 0, v3 = 0;
  if (base + 0 < n) v0 = deg[base + 0];
  if (base + 1 < n) v1 = deg[base + 1];
  if (base + 2 < n) v2 = deg[base + 2];
  if (base + 3 < n) v3 = deg[base + 3];
  int sum = v0 + v1 + v2 + v3;
  s[t] = sum;
  __syncthreads();
  for (int off = 1; off < 256; off <<= 1) {
    int x = (t >= off) ? s[t - off] : 0;
    __syncthreads();
    s[t] += x;
    __syncthreads();
  }
  int excl = s[t] - sum;
  if (t == 255) bsums[blockIdx.x] = s[255];
  if (base + 0 < n) row_off[base + 0] = excl;
  if (base + 1 < n) row_off[base + 1] = excl + v0;
  if (base + 2 < n) row_off[base + 2] = excl + v0 + v1;
  if (base + 3 < n) row_off[base + 3] = excl + v0 + v1 + v2;
}

__global__ __launch_bounds__(128) void scan2_kernel(
    int* __restrict__ bsums, int nb, int* __restrict__ row_off, int n) {
  __shared__ int s[128];
  int t = threadIdx.x;
  int v = (t < nb) ? bsums[t] : 0;
  s[t] = v;
  __syncthreads();
  for (int off = 1; off < 128; off <<= 1) {
    int x = (t >= off) ? s[t - off] : 0;
    __syncthreads();
    s[t] += x;
    __syncthreads();
  }
  if (t < nb) bsums[t] = s[t] - v;
  if (t == 127) row_off[n] = s[127];
}

__global__ __launch_bounds__(256) void scan3_kernel(
    int* __restrict__ row_off, const int* __restrict__ bsums, int n) {
  int i = blockIdx.x * 256 + threadIdx.x;
  if (i < n) row_off[i] += bsums[i >> 10];
}

// ---------------- CSR fill (atomic-free) ----------------

__global__ __launch_bounds__(256) void fill_kernel(
    const int* __restrict__ src, const int* __restrict__ dst,
    const int* __restrict__ row_off, const unsigned char* __restrict__ Pb,
    const unsigned char* __restrict__ lrank, int* __restrict__ csr, int e) {
  int i = blockIdx.x * 256 + threadIdx.x;
  if (i < e) {
    int d = dst[i];
    int c = i >> CBITS;
    int pos = row_off[d] + (int)Pb[(size_t)c * NN + d] + (int)lrank[i];
    csr[pos] = src[i];
  }
}

// ---------------- bf16 helpers ----------------

__device__ __forceinline__ uint pack_bf16(float a, float b) {
  uint ua = __float_as_uint(a), ub = __float_as_uint(b);
  ua = (ua + 0x7fffu + ((ua >> 16) & 1u)) >> 16;          // RNE
  ub = (ub + 0x7fffu + ((ub >> 16) & 1u)) & 0xffff0000u;  // RNE
  return ua | ub;  // a -> low ushort (even idx), b -> high (odd idx)
}

__device__ __forceinline__ ushort to_bf16(float a) {
  uint ua = __float_as_uint(a);
  return (ushort)((ua + 0x7fffu + ((ua >> 16) & 1u)) >> 16);
}

union U16 {
  uint4 u;
  short8 s;
};
__device__ __forceinline__ short8 as_short8(uint4 u) {
  U16 t;
  t.u = u;
  return t.s;
}

__device__ __forceinline__ f32x2 bf2(uint u) {
  f32x2 r;
  r.x = __uint_as_float(u << 16);
  r.y = __uint_as_float(u & 0xffff0000u);
  return r;
}

__device__ __forceinline__ void add8(f32x2* a, uint4 v) {
  a[0] += bf2(v.x);
  a[1] += bf2(v.y);
  a[2] += bf2(v.z);
  a[3] += bf2(v.w);
}

// ---------------- weight transpose + bf16 convert ----------------

__global__ __launch_bounds__(256) void transw_kernel(
    const float* __restrict__ W1, const float* __restrict__ W2,
    const float* __restrict__ W3, ushort* __restrict__ Wt1,
    ushort* __restrict__ Wt2, ushort* __restrict__ Wt3) {
  int i = blockIdx.x * 256 + threadIdx.x;  // 0..24575
  if (i < 8192) {
    int n = i >> 7, k = i & 127;
    Wt1[i] = to_bf16(W1[k * 64 + n]);
  } else if (i < 16384) {
    int j = i - 8192;
    int n = j >> 6, k = j & 63;
    Wt2[j] = to_bf16(W2[k * 128 + n]);
  } else if (i < 24576) {
    int j = i - 16384;
    int n = j >> 7, k = j & 127;
    Wt3[j] = to_bf16(W3[k * 64 + n]);
  }
}

// ---------------- skinny MFMA GEMM (layer 1): t1 = bf16((A@W1)*ns) --------
// A: [n][128] fp32 (inline bf16 convert), Wt: [64][128] bf16, C: [n][64].
// mfma_f32_16x16x32_bf16: A-frag A[m=lane&15][k=quad*8+j], C/D col=lane&15,
// row=quad*4+reg  [learn_hip m89 verified].

__global__ __launch_bounds__(256) void gemm1_kernel(
    const float* __restrict__ A, const ushort* __restrict__ Wt,
    const float* __restrict__ scale, ushort* __restrict__ C, int n) {
  int wid = threadIdx.x >> 6, lane = threadIdx.x & 63;
  int r = lane & 15, quad = lane >> 4;
  int m16 = blockIdx.x * 64 + wid * 16;
  if (m16 >= n) return;
  int mc = min(m16 + r, n - 1);
  short8 a[4];
#pragma unroll
  for (int ks = 0; ks < 4; ++ks) {
    const float4* p = (const float4*)(A + (size_t)mc * 128 + ks * 32 + quad * 8);
    float4 x = p[0], y = p[1];
    uint4 u;
    u.x = pack_bf16(x.x, x.y);
    u.y = pack_bf16(x.z, x.w);
    u.z = pack_bf16(y.x, y.y);
    u.w = pack_bf16(y.z, y.w);
    a[ks] = as_short8(u);
  }
#pragma unroll
  for (int nt = 0; nt < 4; ++nt) {
    f32x4 acc = {0.f, 0.f, 0.f, 0.f};
#pragma unroll
    for (int ks = 0; ks < 4; ++ks) {
      short8 b = as_short8(
          *(const uint4*)(Wt + (size_t)(nt * 16 + r) * 128 + ks * 32 + quad * 8));
      acc = __builtin_amdgcn_mfma_f32_16x16x32_bf16(a[ks], b, acc, 0, 0, 0);
    }
#pragma unroll
    for (int reg = 0; reg < 4; ++reg) {
      int m = m16 + quad * 4 + reg;
      if (m < n) C[(size_t)m * 64 + nt * 16 + r] = to_bf16(acc[reg] * scale[m]);
    }
  }
}

// ------- fused layers 2+3 dense: t3 = (relu(m2@W2+b2)*ns) @ W3 ------------
// First MFMA (K=64,N=128) -> epilogue -> bf16 tile in LDS (padded 136) ->
// A-frags for second MFMA (K=128,N=64). Same-wave LDS write->read only.

__global__ __launch_bounds__(256) void gemm23_kernel(
    const ushort* __restrict__ m2, const ushort* __restrict__ Wt2,
    const float* __restrict__ b2, const float* __restrict__ ns,
    const ushort* __restrict__ Wt3, ushort* __restrict__ t3, int n) {
  __shared__ ushort sX[4][16][136];  // 17.4KB, pad keeps 16B align
  int wid = threadIdx.x >> 6, lane = threadIdx.x & 63;
  int r = lane & 15, quad = lane >> 4;
  int m16 = blockIdx.x * 64 + wid * 16;
  if (m16 >= n) return;
  int mc = min(m16 + r, n - 1);
  short8 a1[2];
#pragma unroll
  for (int ks = 0; ks < 2; ++ks)
    a1[ks] = as_short8(*(const uint4*)(m2 + (size_t)mc * 64 + ks * 32 + quad * 8));
  float nsv[4];
#pragma unroll
  for (int reg = 0; reg < 4; ++reg)
    nsv[reg] = ns[min(m16 + quad * 4 + reg, n - 1)];
#pragma unroll
  for (int nt = 0; nt < 8; ++nt) {
    f32x4 acc = {0.f, 0.f, 0.f, 0.f};
#pragma unroll
    for (int ks = 0; ks < 2; ++ks) {
      short8 b = as_short8(
          *(const uint4*)(Wt2 + (size_t)(nt * 16 + r) * 64 + ks * 32 + quad * 8));
      acc = __builtin_amdgcn_mfma_f32_16x16x32_bf16(a1[ks], b, acc, 0, 0, 0);
    }
    float bv = b2[nt * 16 + r];
#pragma unroll
    for (int reg = 0; reg < 4; ++reg) {
      float v = fmaxf(acc[reg] + bv, 0.f) * nsv[reg];
      sX[wid][quad * 4 + reg][nt * 16 + r] = to_bf16(v);
    }
  }
  short8 a2[4];
#pragma unroll
  for (int ks = 0; ks < 4; ++ks)
    a2[ks] = as_short8(*(const uint4*)(&sX[wid][r][ks * 32 + quad * 8]));
#pragma unroll
  for (int nt = 0; nt < 4; ++nt) {
    f32x4 acc = {0.f, 0.f, 0.f, 0.f};
#pragma unroll
    for (int ks = 0; ks < 4; ++ks) {
      short8 b = as_short8(
          *(const uint4*)(Wt3 + (size_t)(nt * 16 + r) * 128 + ks * 32 + quad * 8));
      acc = __builtin_amdgcn_mfma_f32_16x16x32_bf16(a2[ks], b, acc, 0, 0, 0);
    }
#pragma unroll
    for (int reg = 0; reg < 4; ++reg) {
      int m = m16 + quad * 4 + reg;
      if (m < n) t3[(size_t)m * 64 + nt * 16 + r] = to_bf16(acc[reg]);
    }
  }
}

// ---------------- paired 64-feature bf16 CSR gather ----------------
// One wave gathers TWO adjacent dst rows over the combined contiguous csr
// range [rs, re), boundary rm. 8 lanes/edge, uint4 = 8 bf16 features/lane.

__device__ __forceinline__ void gather2_bf16(const int* __restrict__ csr,
                                             const ushort* __restrict__ x,
                                             int rs, int rm, int re, int lane,
                                             f32x2* a0, f32x2* a1) {
  const int eg = lane >> 3;
  const int fl = lane & 7;
  for (int e0 = rs; e0 < re; e0 += 64) {
    int idx = e0 + lane;
    int sv = (idx < re) ? csr[idx] : 0;
    int cnt = re - e0;
    if (cnt > 64) cnt = 64;
    int c0 = rm - e0;  // slots < c0 belong to node0
#pragma unroll
    for (int j = 0; j < 8; ++j) {
      int jb = j * 8;
      if (jb < cnt) {  // wave-uniform
        int s = __shfl(sv, jb + eg);
        uint4 v = *(const uint4*)(x + (size_t)s * 64 + fl * 8);
        if (jb + 8 > cnt) {  // partial tail: mask invalid edge-groups
          uint mv = ((jb + eg) < cnt) ? 0xffffffffu : 0u;
          v.x &= mv; v.y &= mv; v.z &= mv; v.w &= mv;
        }
        if (jb + 8 <= c0) {
          add8(a0, v);
        } else if (jb >= c0) {
          add8(a1, v);
        } else {  // straddles the node boundary
          uint m0 = ((jb + eg) < c0) ? 0xffffffffu : 0u;
          uint4 v0;
          v0.x = v.x & m0; v0.y = v.y & m0; v0.z = v.z & m0; v0.w = v.w & m0;
          add8(a0, v0);
          v.x ^= v0.x; v.y ^= v0.y; v.z ^= v0.z; v.w ^= v0.w;
          add8(a1, v);
        }
      }
    }
  }
#pragma unroll
  for (int k = 0; k < 4; ++k) {
    a0[k].x += __shfl_xor(a0[k].x, 8);
    a0[k].x += __shfl_xor(a0[k].x, 16);
    a0[k].x += __shfl_xor(a0[k].x, 32);
    a0[k].y += __shfl_xor(a0[k].y, 8);
    a0[k].y += __shfl_xor(a0[k].y, 16);
    a0[k].y += __shfl_xor(a0[k].y, 32);
    a1[k].x += __shfl_xor(a1[k].x, 8);
    a1[k].x += __shfl_xor(a1[k].x, 16);
    a1[k].x += __shfl_xor(a1[k].x, 32);
    a1[k].y += __shfl_xor(a1[k].y, 8);
    a1[k].y += __shfl_xor(a1[k].y, 16);
    a1[k].y += __shfl_xor(a1[k].y, 32);
  }
}

// select feature k (0..7) of the proper node's accumulator
#define ACC_SEL(k) ((eg == 0) ? a0[(k) >> 1][(k)&1] : a1[(k) >> 1][(k)&1])

// ---------------- layer 1 aggregate + epilogue (bf16 out) ----------------

__global__ __launch_bounds__(256) void agg1_kernel(
    const int* __restrict__ row_off, const int* __restrict__ csr,
    const ushort* __restrict__ t, const float* __restrict__ nd,
    const float* __restrict__ ns, const float* __restrict__ b,
    ushort* __restrict__ out, int n) {
  int wid = threadIdx.x >> 6, lane = threadIdx.x & 63;
  int n0 = blockIdx.x * 8 + wid * 2;  // n % 8 == 0
  int rs = row_off[n0], rm = row_off[n0 + 1], re = row_off[n0 + 2];
  f32x2 a0[4] = {{0, 0}, {0, 0}, {0, 0}, {0, 0}};
  f32x2 a1[4] = {{0, 0}, {0, 0}, {0, 0}, {0, 0}};
  gather2_bf16(csr, t, rs, rm, re, lane, a0, a1);
  int eg = lane >> 3, fl = lane & 7;
  if (eg < 2) {  // eg==0 -> node0, eg==1 -> node1
    int node = n0 + eg;
    float ndv = nd[node], nsv = ns[node];
    const float4* bp = (const float4*)(b + fl * 8);
    float4 b0 = bp[0], b1v = bp[1];
    float o0 = fmaxf(ACC_SEL(0) * ndv + b0.x, 0.f) * nsv;
    float o1 = fmaxf(ACC_SEL(1) * ndv + b0.y, 0.f) * nsv;
    float o2 = fmaxf(ACC_SEL(2) * ndv + b0.z, 0.f) * nsv;
    float o3 = fmaxf(ACC_SEL(3) * ndv + b0.w, 0.f) * nsv;
    float o4 = fmaxf(ACC_SEL(4) * ndv + b1v.x, 0.f) * nsv;
    float o5 = fmaxf(ACC_SEL(5) * ndv + b1v.y, 0.f) * nsv;
    float o6 = fmaxf(ACC_SEL(6) * ndv + b1v.z, 0.f) * nsv;
    float o7 = fmaxf(ACC_SEL(7) * ndv + b1v.w, 0.f) * nsv;
    uint4 v;
    v.x = pack_bf16(o0, o1);
    v.y = pack_bf16(o2, o3);
    v.z = pack_bf16(o4, o5);
    v.w = pack_bf16(o6, o7);
    *(uint4*)(out + (size_t)node * 64 + fl * 8) = v;
  }
}

// ---------------- layer 2 aggregate (gather-only, bf16 out) ----------------

__global__ __launch_bounds__(256) void agg2_kernel(
    const int* __restrict__ row_off, const int* __restrict__ csr,
    const ushort* __restrict__ h1s, const float* __restrict__ nd,
    ushort* __restrict__ m2, int n) {
  int wid = threadIdx.x >> 6, lane = threadIdx.x & 63;
  int n0 = blockIdx.x * 8 + wid * 2;
  int rs = row_off[n0], rm = row_off[n0 + 1], re = row_off[n0 + 2];
  f32x2 a0[4] = {{0, 0}, {0, 0}, {0, 0}, {0, 0}};
  f32x2 a1[4] = {{0, 0}, {0, 0}, {0, 0}, {0, 0}};
  gather2_bf16(csr, h1s, rs, rm, re, lane, a0, a1);
  int eg = lane >> 3, fl = lane & 7;
  if (eg < 2) {
    int node = n0 + eg;
    float ndv = nd[node];
    uint4 v;
    v.x = pack_bf16(ACC_SEL(0) * ndv, ACC_SEL(1) * ndv);
    v.y = pack_bf16(ACC_SEL(2) * ndv, ACC_SEL(3) * ndv);
    v.z = pack_bf16(ACC_SEL(4) * ndv, ACC_SEL(5) * ndv);
    v.w = pack_bf16(ACC_SEL(6) * ndv, ACC_SEL(7) * ndv);
    *(uint4*)(m2 + (size_t)node * 64 + fl * 8) = v;
  }
}

// ---------------- layer 3 aggregate + block-reduced readout ----------------

__global__ __launch_bounds__(512) void agg3_kernel(
    const int* __restrict__ row_off, const int* __restrict__ csr,
    const ushort* __restrict__ t, const float* __restrict__ nd,
    const float* __restrict__ b, const int* __restrict__ gid,
    float* __restrict__ hg, int n) {
  __shared__ float sO[16][64];
  __shared__ int sG[16];
  __shared__ int uni;
  int wid = threadIdx.x >> 6, lane = threadIdx.x & 63;
  int n0 = blockIdx.x * 16 + wid * 2;  // NN % 16 == 0
  int rs = row_off[n0], rm = row_off[n0 + 1], re = row_off[n0 + 2];
  f32x2 a0[4] = {{0, 0}, {0, 0}, {0, 0}, {0, 0}};
  f32x2 a1[4] = {{0, 0}, {0, 0}, {0, 0}, {0, 0}};
  gather2_bf16(csr, t, rs, rm, re, lane, a0, a1);
  int eg = lane >> 3, fl = lane & 7;
  if (eg < 2) {
    int node = n0 + eg;
    int row = wid * 2 + eg;
    float ndv = nd[node];
    const float4* bp = (const float4*)(b + fl * 8);
    float4 b0 = bp[0], b1v = bp[1];
    sO[row][fl * 8 + 0] = fmaxf(ACC_SEL(0) * ndv + b0.x, 0.f);
    sO[row][fl * 8 + 1] = fmaxf(ACC_SEL(1) * ndv + b0.y, 0.f);
    sO[row][fl * 8 + 2] = fmaxf(ACC_SEL(2) * ndv + b0.z, 0.f);
    sO[row][fl * 8 + 3] = fmaxf(ACC_SEL(3) * ndv + b0.w, 0.f);
    sO[row][fl * 8 + 4] = fmaxf(ACC_SEL(4) * ndv + b1v.x, 0.f);
    sO[row][fl * 8 + 5] = fmaxf(ACC_SEL(5) * ndv + b1v.y, 0.f);
    sO[row][fl * 8 + 6] = fmaxf(ACC_SEL(6) * ndv + b1v.z, 0.f);
    sO[row][fl * 8 + 7] = fmaxf(ACC_SEL(7) * ndv + b1v.w, 0.f);
  }
  if (lane == 0) sG[wid * 2] = gid[n0];
  if (lane == 8) sG[wid * 2 + 1] = gid[n0 + 1];
  __syncthreads();
  if (threadIdx.x == 0) {
    int g0 = sG[0], u = 1;
#pragma unroll
    for (int i = 1; i < 16; ++i) u &= (sG[i] == g0);
    uni = u;
  }
  __syncthreads();
  if (uni) {
    int r = threadIdx.x >> 6;  // 0..7
#pragma unroll
    for (int s = 8; s >= 1; s >>= 1) {
      if (r < s) sO[r][lane] += sO[r + s][lane];
      __syncthreads();
    }
    if (threadIdx.x < 64) atomicAdd(&hg[sG[0] * 64 + lane], sO[0][lane]);
  } else {
    atomicAdd(&hg[sG[wid * 2] * 64 + lane], sO[wid * 2][lane]);
    atomicAdd(&hg[sG[wid * 2 + 1] * 64 + lane], sO[wid * 2 + 1][lane]);
  }
}

// ---------------- readout dense ----------------

__global__ __launch_bounds__(640) void readout_kernel(
    const float* __restrict__ hg, const float* __restrict__ Wd,
    const float* __restrict__ bd, float* __restrict__ out) {
  int t = threadIdx.x;  // 640 = 64 graphs * 10 classes
  int g = t / 10, c = t % 10;
  float o = bd[c];
#pragma unroll 8
  for (int k = 0; k < 64; ++k) o += tanhf(hg[g * 64 + k]) * Wd[k * 10 + c];
  out[t] = o;
}

// ---------------- launch ----------------

extern "C" void kernel_launch(void* const* d_in, const int* in_sizes, int n_in,
                              void* d_out, int out_size, void* d_ws, size_t ws_size,
                              hipStream_t stream) {
  const float* in_feat = (const float*)d_in[0];
  const int* src = (const int*)d_in[1];
  const int* dst = (const int*)d_in[2];
  const int* gid = (const int*)d_in[3];
  const float* W1 = (const float*)d_in[4];
  const float* b1 = (const float*)d_in[5];
  const float* W2 = (const float*)d_in[6];
  const float* b2 = (const float*)d_in[7];
  const float* W3 = (const float*)d_in[8];
  const float* b3 = (const float*)d_in[9];
  const float* Wd = (const float*)d_in[10];
  const float* bd = (const float*)d_in[11];
  float* out = (float*)d_out;

  char* ws = (char*)d_ws;
  size_t o = 0;
  auto alloc = [&](size_t bytes) -> char* {
    char* p = ws + o;
    o = (o + bytes + 1023) & ~(size_t)1023;
    return p;
  };
  float* hg = (float*)alloc(NG * 64 * 4);
  size_t zero_bytes = o;  // only hg needs zero-init
  int* deg_in = (int*)alloc(NN * 4);
  float* norm_src = (float*)alloc(NN * 4);
  float* norm_dst = (float*)alloc(NN * 4);
  int* row_off = (int*)alloc((NN + 1) * 4);
  int* bsums = (int*)alloc(512);
  ushort* Wt1 = (ushort*)alloc(64 * 128 * 2);
  ushort* Wt2 = (ushort*)alloc(128 * 64 * 2);
  ushort* Wt3 = (ushort*)alloc(64 * 128 * 2);
  int* csr = (int*)alloc((size_t)NE * 4);
  ushort* tbuf = (ushort*)alloc((size_t)NN * 64 * 2);  // bf16 t1, then t3
  ushort* h1s = (ushort*)alloc((size_t)NN * 64 * 2);   // bf16
  ushort* m2 = (ushort*)alloc((size_t)NN * 64 * 2);    // bf16
  (void)ws_size;

  // overlays on [tbuf..m2+12.8MB) (38.4MB contiguous): all CSR-build scratch
  // is dead before gemm1 (tbuf), agg1 (h1s), agg2 (m2) first write.
  char* ov = (char*)tbuf;
  uint* pdst = (uint*)ov;                                 // 2.45MB
  uint* psrc = (uint*)(ov + 2457600);                     // 2.45MB
  unsigned char* Pb = (unsigned char*)(ov + 4915200);     // 4.9MB
  unsigned char* lrank = (unsigned char*)(ov + 9830400);  // 3.2MB

  hipMemsetAsync(d_ws, 0, zero_bytes, stream);

  const int egrid = (NE + 255) / 256;      // 12500
  const int ngrid = (NN + 255) / 256;      // 391
  const int sgrid = (NN + 1023) / 1024;    // 98
  const int wgrid2 = NN / 8;               // 12500 (pair-gather)
  const int rgrid = (WORDS4 + 255) / 256;  // 49
  const int ggrid = (NN + 63) / 64;        // 1563

  transw_kernel<<<96, 256, 0, stream>>>(W1, W2, W3, Wt1, Wt2, Wt3);
  hist_kernel<<<dim3(NCHUNK, 2), 1024, 0, stream>>>(src, dst, pdst, psrc, lrank);
  reduce2_kernel<<<dim3(rgrid, 2), 256, 0, stream>>>(pdst, psrc, Pb, deg_in,
                                                     norm_dst, norm_src);
  scan1_kernel<<<sgrid, 256, 0, stream>>>(deg_in, row_off, bsums, NN);
  scan2_kernel<<<1, 128, 0, stream>>>(bsums, sgrid, row_off, NN);
  scan3_kernel<<<ngrid, 256, 0, stream>>>(row_off, bsums, NN);
  fill_kernel<<<egrid, 256, 0, stream>>>(src, dst, row_off, Pb, lrank, csr, NE);

  // layer 1: t1 = bf16((in_feat @ W1) * ns)   [MFMA]
  gemm1_kernel<<<ggrid, 256, 0, stream>>>(in_feat, Wt1, norm_src, tbuf, NN);
  // h1s = bf16(relu(seg(t1)*nd + b1) * ns)
  agg1_kernel<<<wgrid2, 256, 0, stream>>>(row_off, csr, tbuf, norm_dst,
                                          norm_src, b1, h1s, NN);
  // m2 = bf16(seg(h1s)*nd)
  agg2_kernel<<<wgrid2, 256, 0, stream>>>(row_off, csr, h1s, norm_dst, m2, NN);
  // t3 = bf16((relu(m2@W2+b2)*ns) @ W3)   [fused MFMA x2]
  gemm23_kernel<<<ggrid, 256, 0, stream>>>(m2, Wt2, b2, norm_src, Wt3, tbuf, NN);
  // hg[g] += relu(seg(t3)*nd + b3)
  agg3_kernel<<<NN / 16, 512, 0, stream>>>(row_off, csr, tbuf, norm_dst, b3,
                                           gid, hg, NN);
  readout_kernel<<<1, 640, 0, stream>>>(hg, Wd, bd, out);
}